// Round 12
// baseline (1817.120 us; speedup 1.0000x reference)
//
#include <hip/hip_runtime.h>
#include <hip/hip_bf16.h>
#include <hip/hip_fp16.h>
#include <cstdint>
#include <cstddef>

#define B_   512
#define T_   128
#define D_   512
#define H_   512
#define MID_ 38
#define BOT_ 38
#define S_   26
#define XL_  588   // D + MID + BOT = W_ih row length

typedef unsigned short u16;
typedef __attribute__((ext_vector_type(8))) short bf16x8v;
typedef __attribute__((ext_vector_type(8))) _Float16 f16x8v;
typedef __attribute__((ext_vector_type(8))) unsigned short u16x8;
typedef __attribute__((ext_vector_type(4))) float f32x4v;

__device__ __forceinline__ u16 f2bf_rn(float f){
  unsigned u = __float_as_uint(f);
  return (u16)((u + 0x7fffu + ((u>>16)&1u)) >> 16);
}
__device__ __forceinline__ float bf2f(u16 v){ return __uint_as_float(((unsigned)v)<<16); }
__device__ __forceinline__ u16 f2h_u(float f){ return __half_as_ushort(__float2half(f)); }
__device__ __forceinline__ float h2f_u(u16 u){ return __half2float(__ushort_as_half(u)); }

// branch-free fast transcendentals (v_exp_f32 + v_rcp_f32, ~1e-6 rel err)
__device__ __forceinline__ float fast_tanh(float x){
  return 1.0f - 2.0f*__builtin_amdgcn_rcpf(__expf(2.0f*x) + 1.0f);
}
__device__ __forceinline__ float fast_sig(float x){
  return __builtin_amdgcn_rcpf(1.0f + __expf(-x));
}

// async global->LDS, 16B per lane.  LDS dest must be wave-uniform base +
// lane*16 (our t*16B staging layout satisfies this); global src is per-lane.
typedef __attribute__((address_space(1))) const unsigned gu32;
typedef __attribute__((address_space(3))) unsigned lu32;
__device__ __forceinline__ void gload16(const void* g, void* l){
  __builtin_amdgcn_global_load_lds((gu32*)g, (lu32*)l, 16, 0, 0);
}

// ---------------------------------------------------------------------------
// One-shot setup: bH->fp16, weight conversions, token tables, bias combine,
// h/c zero-init.  Flat quad-index space, grid-stride.
// ---------------------------------------------------------------------------
__device__ __forceinline__ void cvt_hilo4(const float* src, u16* hi, u16* lo){
  float4 v = *(const float4*)src;
  ushort4 h, l;
  h.x=f2bf_rn(v.x); h.y=f2bf_rn(v.y); h.z=f2bf_rn(v.z); h.w=f2bf_rn(v.w);
  l.x=f2bf_rn(v.x-bf2f(h.x)); l.y=f2bf_rn(v.y-bf2f(h.y));
  l.z=f2bf_rn(v.z-bf2f(h.z)); l.w=f2bf_rn(v.w-bf2f(h.w));
  *(ushort4*)hi = h; *(ushort4*)lo = l;
}

__global__ __launch_bounds__(256) void setup_all(
    const float* __restrict__ bH,
    const float* __restrict__ Wi2h, const float* __restrict__ Wh2h,
    const float* __restrict__ Whh,  const float* __restrict__ Wih,
    const float* __restrict__ Wgen, const float* __restrict__ bh2h,
    const float* __restrict__ bih,  const float* __restrict__ bhh,
    u16* __restrict__ bHh,
    u16* __restrict__ Wi2h_h, u16* __restrict__ Bh2_hi, u16* __restrict__ Bh2_lo,
    u16* __restrict__ Bih_hi, u16* __restrict__ Bih_lo,
    u16* __restrict__ Wg_hi,  u16* __restrict__ Wg_lo,
    float* __restrict__ WmT, float* __restrict__ WbT, float* __restrict__ bcombF,
    u16* __restrict__ hA_hi, u16* __restrict__ hA_lo, float* __restrict__ c)
{
  const int T0 = 8388608;               // bH -> fp16 (65536 rows x 128 quads)
  const int T1 = T0+65536;              // Wi2h -> fp16
  const int T2 = T1+65536;              // Wh2h -> Bh2[0:512] hi/lo
  const int T3 = T2+262144;             // Whh  -> Bh2[512:2560]
  const int T4 = T3+262144;             // Wih[:, :512] -> Bih
  const int T5 = T4+8192;               // Wgen -> Wg (pad 64 rows)
  const int T6 = T5+19456;              // token tables (38*512 quads)
  const int T7 = T6+640;                // bcombF
  const int T8 = T7+65536;              // hA hi/lo zero (ushort4 each)
  const int T9 = T8+65536;              // c zero (float4)
  for (int i = blockIdx.x*256 + threadIdx.x; i < T9; i += gridDim.x*256){
    if (i < T0){
      int row=i>>7, c4=(i&127)*4;
      float4 v = *(const float4*)&bH[(size_t)row*512 + c4];
      ushort4 h; h.x=f2h_u(v.x); h.y=f2h_u(v.y); h.z=f2h_u(v.z); h.w=f2h_u(v.w);
      *(ushort4*)&bHh[(size_t)row*512 + c4] = h;
    } else if (i < T1){
      int j=i-T0, row=j>>7, c4=(j&127)*4;
      float4 v = *(const float4*)&Wi2h[(size_t)row*512 + c4];
      ushort4 h; h.x=f2h_u(v.x); h.y=f2h_u(v.y); h.z=f2h_u(v.z); h.w=f2h_u(v.w);
      *(ushort4*)&Wi2h_h[(size_t)row*512 + c4] = h;
    } else if (i < T2){
      int j=i-T1, row=j>>7, c4=(j&127)*4;
      cvt_hilo4(&Wh2h[(size_t)row*512+c4], &Bh2_hi[(size_t)row*512+c4], &Bh2_lo[(size_t)row*512+c4]);
    } else if (i < T3){
      int j=i-T2, row=j>>7, c4=(j&127)*4;
      cvt_hilo4(&Whh[(size_t)row*512+c4],
                &Bh2_hi[(size_t)(512+row)*512+c4], &Bh2_lo[(size_t)(512+row)*512+c4]);
    } else if (i < T4){
      int j=i-T3, row=j>>7, c4=(j&127)*4;
      cvt_hilo4(&Wih[(size_t)row*XL_+c4], &Bih_hi[(size_t)row*512+c4], &Bih_lo[(size_t)row*512+c4]);
    } else if (i < T5){
      int j=i-T4, row=j>>7, c4=(j&127)*4;
      float4 v = make_float4(0.f,0.f,0.f,0.f);
      if (row < MID_) v = *(const float4*)&Wgen[(size_t)row*512 + c4];
      ushort4 h, l;
      h.x=f2bf_rn(v.x); h.y=f2bf_rn(v.y); h.z=f2bf_rn(v.z); h.w=f2bf_rn(v.w);
      l.x=f2bf_rn(v.x-bf2f(h.x)); l.y=f2bf_rn(v.y-bf2f(h.y));
      l.z=f2bf_rn(v.z-bf2f(h.z)); l.w=f2bf_rn(v.w-bf2f(h.w));
      *(ushort4*)&Wg_hi[(size_t)row*512+c4] = h;
      *(ushort4*)&Wg_lo[(size_t)row*512+c4] = l;
    } else if (i < T6){
      int j=i-T5;                    // 38*512
      int cc=j>>9, jq=j&511;
#pragma unroll
      for (int u=0;u<4;u++){
        int jj=jq*4+u;
        WmT[(size_t)cc*2048+jj] = Wih[(size_t)jj*XL_ + 512 + cc];
        WbT[(size_t)cc*2048+jj] = Wih[(size_t)jj*XL_ + 512 + MID_ + cc];
      }
    } else if (i < T7){
      int j=(i-T6)*4;
#pragma unroll
      for (int u=0;u<4;u++){
        int k=j+u;
        if (k < 512) bcombF[k] = bh2h[k];
        else if (k < 2560) bcombF[k] = bih[k-512] + bhh[k-512];
      }
    } else if (i < T8){
      int j=i-T7;
      ushort4 z = {0,0,0,0};
      *(ushort4*)&hA_hi[(size_t)j*4] = z;
      *(ushort4*)&hA_lo[(size_t)j*4] = z;
    } else {
      int j=i-T8;
      *(float4*)&c[(size_t)j*4] = make_float4(0.f,0.f,0.f,0.f);
    }
  }
}

// ---------------------------------------------------------------------------
// proj GEMM, pure fp16, BM=BN=128, XCD-aware 1D grid (2048 blocks),
// global_load_lds staging (linear LDS, stride 32 shorts).
// A = bHh fp16, B = Wi2h fp16.  C = fp16 projh via LDS bounce.
// ---------------------------------------------------------------------------
__global__ __launch_bounds__(256) void gemm_proj16(
    const u16* __restrict__ Ah, const u16* __restrict__ Bh,
    u16* __restrict__ projh)
{
  extern __shared__ char smem[];
  short* As = (short*)smem;                  // [128][32] linear
  short* Bs = As + 128*32;
  const int tid=threadIdx.x;
  const int n = blockIdx.x;
  const int x = n & 7, q = n >> 3;
  const int bn = (q & 3) * 128;
  const int bm = ((q >> 2)*8 + x) * 128;
  const int w=tid>>6, lane=tid&63, wr=w>>1, wc=w&1;

  f32x4v acc[4][4];
#pragma unroll
  for (int i=0;i<4;i++)
#pragma unroll
    for (int j=0;j<4;j++) acc[i][j] = (f32x4v){0.f,0.f,0.f,0.f};

  for (int it=0; it<16; ++it){
    const int kk = it<<5;
#pragma unroll
    for (int L=0; L<2; L++){
      int t=L*256+tid, row=t>>2, c=(t&3)*8;
      gload16(&Ah[(size_t)(bm+row)*512 + kk + c], &As[t*8]);
      gload16(&Bh[(size_t)(bn+row)*512 + kk + c], &Bs[t*8]);
    }
    __syncthreads();                 // drains vmcnt -> LDS tiles ready
    const int koff = (lane>>4)*8, mrow = lane&15;
#pragma unroll
    for (int i=0;i<4;i++)
#pragma unroll
      for (int j=0;j<4;j++){
        f16x8v af = *(const f16x8v*)&As[(wr*64+i*16+mrow)*32 + koff];
        f16x8v bf = *(const f16x8v*)&Bs[(wc*64+j*16+mrow)*32 + koff];
        acc[i][j] = __builtin_amdgcn_mfma_f32_16x16x32_f16(af, bf, acc[i][j], 0,0,0);
      }
    __syncthreads();                 // reads done before next overwrite
  }

  // epilogue: fp16 out via LDS bounce
  const int r0 = (lane>>4)*4, cn = lane&15;
  u16* Ts = (u16*)smem;   // [128][128]
#pragma unroll
  for (int i=0;i<4;i++)
#pragma unroll
    for (int j=0;j<4;j++)
#pragma unroll
      for (int r=0;r<4;r++)
        Ts[(wr*64+i*16+r0+r)*128 + wc*64+j*16+cn] = f2h_u(acc[i][j][r]);
  __syncthreads();
#pragma unroll
  for (int q2=0;q2<8;q2++){
    int idx = q2*256 + tid;
    int row = idx>>4, c8 = (idx&15)*8;
    *(float4*)&projh[(size_t)(bm+row)*512 + bn + c8] = *(const float4*)&Ts[row*128 + c8];
  }
}

// ---------------------------------------------------------------------------
// bf16 MFMA GEMM (hcombo and generator), K = kSteps*32, NT, bf16x2 3-pass,
// global_load_lds staging (linear LDS, stride 32 shorts).
// MODE 0: fp32 out + col-bias.  MODE 2: generator out (m->(s,b), n<38, +bias2).
// ---------------------------------------------------------------------------
template<int BM,int BN,int MODE>
__global__ __launch_bounds__(256) void gemm_bf(
    const u16* __restrict__ Ah, const u16* __restrict__ Al, int lda,
    const u16* __restrict__ Bh, const u16* __restrict__ Bl, int ldb,
    float* __restrict__ Cout, int ldc,
    const float* __restrict__ bias2, int npass, int kSteps)
{
  extern __shared__ char smem[];
  short* As = (short*)smem;                  // [BM][32] linear
  short* Bs = As + BM*32;                    // [BN][32]
  const int tid=threadIdx.x, bm=blockIdx.y*BM, bn=blockIdx.x*BN;
  const int w=tid>>6, lane=tid&63, wr=w>>1, wc=w&1;
  constexpr int WM=BM/2, WN=BN/2, FM=WM/16, FN=WN/16;
  constexpr int LA=BM/64, LB=BN/64;
  const int nIter = npass*kSteps;

  f32x4v acc[FM][FN];
#pragma unroll
  for (int i=0;i<FM;i++)
#pragma unroll
    for (int j=0;j<FN;j++) acc[i][j] = (f32x4v){0.f,0.f,0.f,0.f};

  for (int it=0; it<nIter; ++it){
    const int pass = it/kSteps, kk = (it%kSteps)<<5;
    const u16* Ap = (pass==2)?Al:Ah;
    const u16* Bp = (pass==1)?Bl:Bh;
#pragma unroll
    for (int L=0; L<LA; L++){
      int t=L*256+tid, row=t>>2, c=(t&3)*8;
      gload16(&Ap[(size_t)(bm+row)*lda + kk + c], &As[t*8]);
    }
#pragma unroll
    for (int L=0; L<LB; L++){
      int t=L*256+tid, row=t>>2, c=(t&3)*8;
      gload16(&Bp[(size_t)(bn+row)*ldb + kk + c], &Bs[t*8]);
    }
    __syncthreads();
    const int koff = (lane>>4)*8, mrow = lane&15;
#pragma unroll
    for (int i=0;i<FM;i++)
#pragma unroll
      for (int j=0;j<FN;j++){
        bf16x8v af = *(const bf16x8v*)&As[(wr*WM+i*16+mrow)*32 + koff];
        bf16x8v bf = *(const bf16x8v*)&Bs[(wc*WN+j*16+mrow)*32 + koff];
        acc[i][j] = __builtin_amdgcn_mfma_f32_16x16x32_bf16(af, bf, acc[i][j], 0,0,0);
      }
    __syncthreads();
  }

  const int r0 = (lane>>4)*4, cn = lane&15;
  if constexpr (MODE==2){
#pragma unroll
    for (int i=0;i<FM;i++)
#pragma unroll
      for (int j=0;j<FN;j++)
#pragma unroll
        for (int r=0;r<4;r++){
          int m = bm + wr*WM + i*16 + r0 + r;       // m = s*512 + b
          int n2 = bn + wc*WN + j*16 + cn;
          if (n2 < MID_){
            int s = m >> 9, b = m & 511;
            Cout[((size_t)b*S_ + s)*MID_ + n2] = acc[i][j][r] + bias2[n2];
          }
        }
  } else {
#pragma unroll
    for (int i=0;i<FM;i++)
#pragma unroll
      for (int j=0;j<FN;j++)
#pragma unroll
        for (int r=0;r<4;r++){
          int row = bm + wr*WM + i*16 + r0 + r;
          int col = bn + wc*WN + j*16 + cn;
          float v = acc[i][j][r];
          if (bias2) v += bias2[col];
          Cout[(size_t)row*ldc + col] = v;
        }
  }
}

// ---------------------------------------------------------------------------
// Fused attention, 1024 threads (16 waves):
//   pp from combo[b][0:512] (fp32, ld 2560)
//   e[t] = sum_h Ws[h]*fast_tanh(projh[b,t,h]+pp[h]); single-wave softmax;
//   ctx[b,d] = sum_t alpha[t]*bHh[b,t,d] (4 rows prefetched pre-e-phase).
// ---------------------------------------------------------------------------
__global__ __launch_bounds__(1024) void attn_kernel(
    const u16* __restrict__ projh, const float* __restrict__ combo,
    const float* __restrict__ Wscore, const u16* __restrict__ bHh,
    u16* __restrict__ ctx_hi, u16* __restrict__ ctx_lo)
{
  __shared__ float s_e[T_];
  __shared__ float s_part[16][D_];
  const int tid=threadIdx.x, b=blockIdx.x, wave=tid>>6, lane=tid&63;
  const int d0 = lane*8;
  const u16* cbase = bHh + (size_t)b*T_*D_ + d0;

  float pv[8], wv[8];
  {
    const float* pprow = combo + (size_t)b*2560;
    float4 p0=*(const float4*)&pprow[lane*8], p1=*(const float4*)&pprow[lane*8+4];
    float4 w0=*(const float4*)&Wscore[lane*8], w1=*(const float4*)&Wscore[lane*8+4];
    pv[0]=p0.x;pv[1]=p0.y;pv[2]=p0.z;pv[3]=p0.w;pv[4]=p1.x;pv[5]=p1.y;pv[6]=p1.z;pv[7]=p1.w;
    wv[0]=w0.x;wv[1]=w0.y;wv[2]=w0.z;wv[3]=w0.w;wv[4]=w1.x;wv[5]=w1.y;wv[6]=w1.z;wv[7]=w1.w;
  }
  // prefetch first 4 ctx rows of this wave (consumed after softmax)
  u16x8 pf[4];
#pragma unroll
  for (int r=0;r<4;r++) pf[r] = *(const u16x8*)(cbase + (size_t)(wave*8+r)*D_);

  // e-phase: wave w handles t = w, w+16, ... (8 rows); 2-deep pipeline
  {
    const u16* base = projh + (size_t)b*T_*H_ + lane*8;
    u16x8 cur = *(const u16x8*)(base + (size_t)wave*H_);
    for (int t=wave; t<T_; t+=16){
      u16x8 nxt;
      if (t+16 < T_) nxt = *(const u16x8*)(base + (size_t)(t+16)*H_);
      float acc = 0.f;
#pragma unroll
      for (int j=0;j<8;j++) acc += wv[j]*fast_tanh(h2f_u(cur[j]) + pv[j]);
#pragma unroll
      for (int o=32;o>0;o>>=1) acc += __shfl_down(acc,o);
      if (lane==0) s_e[t] = acc;
      cur = nxt;
    }
  }
  __syncthreads();
  // single-wave softmax over s_e[0..127]
  if (wave==0){
    float v0 = s_e[lane], v1 = s_e[lane+64];
    float mm = fmaxf(v0, v1);
#pragma unroll
    for (int o=32;o>0;o>>=1) mm = fmaxf(mm, __shfl_xor(mm,o));
    float p0 = __expf(v0-mm), p1 = __expf(v1-mm);
    float ss = p0 + p1;
#pragma unroll
    for (int o=32;o>0;o>>=1) ss += __shfl_xor(ss,o);
    const float inv = __builtin_amdgcn_rcpf(ss);
    s_e[lane]    = p0*inv;
    s_e[lane+64] = p1*inv;
  }
  __syncthreads();

  // context: wave w covers t in [8w, 8w+8); rows 0-3 from prefetch regs
  float a[8] = {0,0,0,0,0,0,0,0};
  u16x8 cur = *(const u16x8*)(cbase + (size_t)(wave*8+4)*D_);   // issue early
#pragma unroll
  for (int r=0;r<4;r++){
    const float al = s_e[wave*8+r];
#pragma unroll
    for (int j=0;j<8;j++) a[j] += al*h2f_u(pf[r][j]);
  }
  for (int t=wave*8+4; t<wave*8+8; ++t){
    u16x8 nxt;
    if (t+1 < wave*8+8) nxt = *(const u16x8*)(cbase + (size_t)(t+1)*D_);
    const float al = s_e[t];
#pragma unroll
    for (int j=0;j<8;j++) a[j] += al*h2f_u(cur[j]);
    cur = nxt;
  }
  *(float4*)&s_part[wave][d0]   = make_float4(a[0],a[1],a[2],a[3]);
  *(float4*)&s_part[wave][d0+4] = make_float4(a[4],a[5],a[6],a[7]);
  __syncthreads();
  if (tid < D_){
    float vv = s_part[0][tid];
#pragma unroll
    for (int q=1;q<16;q++) vv += s_part[q][tid];
    u16 hh=f2bf_rn(vv), ll=f2bf_rn(vv-bf2f(hh));
    ctx_hi[(size_t)b*512 + tid] = hh;
    ctx_lo[(size_t)b*512 + tid] = ll;
  }
}

// ---------------------------------------------------------------------------
// Fused gates GEMM + LSTM pointwise (unchanged, proven).  K=512 bf16x2
// 3-pass, BK=64.  gates = ctx @ W_ih[:,:512]^T + combo[:,512:].
// ---------------------------------------------------------------------------
__global__ __launch_bounds__(256) void gates_lstm(
    const u16* __restrict__ Ah, const u16* __restrict__ Al,     // [512][512]
    const u16* __restrict__ Bh, const u16* __restrict__ Bl,     // [2048][512]
    const float* __restrict__ combo,                            // [512][2560]
    const float* __restrict__ WmT, const float* __restrict__ WbT,
    const int* __restrict__ midtok, const int* __restrict__ bottok,
    float* __restrict__ c,
    u16* __restrict__ hA_hi, u16* __restrict__ hA_lo,
    u16* __restrict__ hid_hi, u16* __restrict__ hid_lo, int s)
{
  constexpr int STR = 72;
  __shared__ short Bs[64*STR];
  const int tid=threadIdx.x, lane=tid&63, w=tid>>6;
  const int j0 = blockIdx.x*16, bm = blockIdx.y*64;
  const int mrow=lane&15, koff=(lane>>4)*8;
  const int arow = bm + w*16 + mrow;
  const int srow = tid>>2, scc=(tid&3)*8;
  const int sbrow = (srow>>4)*512 + j0 + (srow&15);

  f32x4v acc[4];
#pragma unroll
  for (int f=0;f<4;f++) acc[f] = (f32x4v){0.f,0.f,0.f,0.f};

  u16x8 sb0, sb1;
  bf16x8v a0[2], a1[2];
  auto loadB = [&](int it){
    const int pass = it>>3, kk=(it&7)<<6;
    const u16* Bp = (pass==1)?Bl:Bh;
    sb0 = *(const u16x8*)&Bp[(size_t)sbrow*512 + kk + scc];
    sb1 = *(const u16x8*)&Bp[(size_t)sbrow*512 + kk + scc + 32];
  };
  auto loadA0 = [&](int it){
    const int pass = it>>3, kk=(it&7)<<6;
    const u16* Ap = (pass==2)?Al:Ah;
    a0[0] = *(const bf16x8v*)&Ap[(size_t)arow*512 + kk + koff];
    a0[1] = *(const bf16x8v*)&Ap[(size_t)arow*512 + kk + koff + 32];
  };
  auto loadA1 = [&](int it){
    const int pass = it>>3, kk=(it&7)<<6;
    const u16* Ap = (pass==2)?Al:Ah;
    a1[0] = *(const bf16x8v*)&Ap[(size_t)arow*512 + kk + koff];
    a1[1] = *(const bf16x8v*)&Ap[(size_t)arow*512 + kk + koff + 32];
  };

  loadB(0); loadA0(0);
  for (int it=0; it<24; it+=2){
    __syncthreads();
    *(u16x8*)&Bs[srow*STR+scc]    = sb0;
    *(u16x8*)&Bs[srow*STR+scc+32] = sb1;
    if (it+1 < 24){ loadB(it+1); loadA1(it+1); }
    __syncthreads();
#pragma unroll
    for (int f=0;f<4;f++){
      bf16x8v b0 = *(const bf16x8v*)&Bs[(f*16+mrow)*STR + koff];
      bf16x8v b1 = *(const bf16x8v*)&Bs[(f*16+mrow)*STR + koff + 32];
      acc[f] = __builtin_amdgcn_mfma_f32_16x16x32_bf16(a0[0], b0, acc[f], 0,0,0);
      acc[f] = __builtin_amdgcn_mfma_f32_16x16x32_bf16(a0[1], b1, acc[f], 0,0,0);
    }
    if (it+1 >= 24) break;
    __syncthreads();
    *(u16x8*)&Bs[srow*STR+scc]    = sb0;
    *(u16x8*)&Bs[srow*STR+scc+32] = sb1;
    if (it+2 < 24){ loadB(it+2); loadA0(it+2); }
    __syncthreads();
#pragma unroll
    for (int f=0;f<4;f++){
      bf16x8v b0 = *(const bf16x8v*)&Bs[(f*16+mrow)*STR + koff];
      bf16x8v b1 = *(const bf16x8v*)&Bs[(f*16+mrow)*STR + koff + 32];
      acc[f] = __builtin_amdgcn_mfma_f32_16x16x32_bf16(a1[0], b0, acc[f], 0,0,0);
      acc[f] = __builtin_amdgcn_mfma_f32_16x16x32_bf16(a1[1], b1, acc[f], 0,0,0);
    }
  }

  // epilogue: lane holds gates f=0..3 for rows r0..r0+3 (b), col jj
  const int r0=(lane>>4)*4, jj=lane&15, j=j0+jj;
#pragma unroll
  for (int r=0;r<4;r++){
    const int b = bm + w*16 + r0 + r;
    const int mt = midtok[b*26 + s];
    const int bt = bottok[b*26 + s];
    const float* wm = WmT + (size_t)mt*2048;
    const float* wb = WbT + (size_t)bt*2048;
    const float* cb = combo + (size_t)b*2560 + 512;
    float ig = acc[0][r] + cb[j       ] + wm[j       ] + wb[j       ];
    float fg = acc[1][r] + cb[512 + j ] + wm[512 + j ] + wb[512 + j ];
    float gg = acc[2][r] + cb[1024 + j] + wm[1024 + j] + wb[1024 + j];
    float og = acc[3][r] + cb[1536 + j] + wm[1536 + j] + wb[1536 + j];
    ig = fast_sig(ig);
    fg = fast_sig(fg);
    gg = fast_tanh(gg);
    og = fast_sig(og);
    const size_t ci = (size_t)b*512 + j;
    const float cn = fg*c[ci] + ig*gg;
    const float hn = og*fast_tanh(cn);
    c[ci] = cn;
    u16 hh = f2bf_rn(hn), hl = f2bf_rn(hn - bf2f(hh));
    hA_hi[ci] = hh;
    hA_lo[ci] = hl;
    hid_hi[((size_t)s*512 + b)*512 + j] = hh;
    hid_lo[((size_t)s*512 + b)*512 + j] = hl;
  }
}

extern "C" void kernel_launch(void* const* d_in, const int* in_sizes, int n_in,
                              void* d_out, int out_size, void* d_ws, size_t ws_size,
                              hipStream_t stream) {
  const float* bH   = (const float*)d_in[0];
  const int*   midt = (const int*)  d_in[1];
  const int*   bott = (const int*)  d_in[2];
  const float* Wi2h = (const float*)d_in[3];
  const float* Wh2h = (const float*)d_in[4];
  const float* bh2h = (const float*)d_in[5];
  const float* Wsc  = (const float*)d_in[6];
  const float* Wih  = (const float*)d_in[7];
  const float* Whh  = (const float*)d_in[8];
  const float* bih  = (const float*)d_in[9];
  const float* bhh  = (const float*)d_in[10];
  const float* Wgen = (const float*)d_in[11];
  const float* bgen = (const float*)d_in[12];
  float* out = (float*)d_out;

  char* wp = (char*)d_ws;
  u16* projh   = (u16*)wp; wp += (size_t)B_*T_*H_*2;      // 67.1 MB fp16
  u16* bHh     = (u16*)wp; wp += (size_t)B_*T_*D_*2;      // 67.1 MB fp16
  u16* Bh2_hi  = (u16*)wp; wp += (size_t)2560*512*2;      // [W_h2h|W_hh] planes
  u16* Bh2_lo  = (u16*)wp; wp += (size_t)2560*512*2;
  u16* Bih_hi  = (u16*)wp; wp += (size_t)2048*512*2;      // W_ih[:, :512] planes
  u16* Bih_lo  = (u16*)wp; wp += (size_t)2048*512*2;
  u16* Wi2h_h  = (u16*)wp; wp += (size_t)512*512*2;       // fp16
  u16* Wg_hi   = (u16*)wp; wp += (size_t)64*512*2;
  u16* Wg_lo   = (u16*)wp; wp += (size_t)64*512*2;
  u16* ctx_hi  = (u16*)wp; wp += (size_t)B_*512*2;
  u16* ctx_lo  = (u16*)wp; wp += (size_t)B_*512*2;
  u16* hA_hi   = (u16*)wp; wp += (size_t)B_*512*2;
  u16* hA_lo   = (u16*)wp; wp += (size_t)B_*512*2;
  u16* hid_hi  = (u16*)wp; wp += (size_t)S_*B_*H_*2;      // 13.6 MB
  u16* hid_lo  = (u16*)wp; wp += (size_t)S_*B_*H_*2;
  float* combo = (float*)wp; wp += (size_t)B_*2560*4;     // 5.2 MB
  float* c     = (float*)wp; wp += (size_t)B_*H_*4;
  float* bcombF= (float*)wp; wp += (size_t)2560*4;
  float* WmT   = (float*)wp; wp += (size_t)MID_*2048*4;
  float* WbT   = (float*)wp; wp += (size_t)BOT_*2048*4;
  if ((size_t)(wp - (char*)d_ws) > ws_size) return;  // fail loudly

  setup_all<<<4096, 256, 0, stream>>>(
      bH, Wi2h, Wh2h, Whh, Wih, Wgen, bh2h, bih, bhh,
      bHh, Wi2h_h, Bh2_hi, Bh2_lo, Bih_hi, Bih_lo, Wg_hi, Wg_lo,
      WmT, WbT, bcombF, hA_hi, hA_lo, c);

  // proj = fp16( bHh @ Wi2h^T ), global_load_lds staging, XCD-aware grid
  gemm_proj16<<<2048, 256, 32768, stream>>>(bHh, Wi2h_h, projh);

  for (int s=0; s<S_; ++s){
    // combo = h @ [W_h2h | W_hh]^T + [b_h2h | b_ih+b_hh]   (bf16x2, N=2560)
    gemm_bf<64,64,0><<<dim3(40,8), 256, 8192, stream>>>(
        hA_hi, hA_lo, 512, Bh2_hi, Bh2_lo, 512,
        combo, 2560, bcombF, 3, 16);
    attn_kernel<<<B_, 1024, 0, stream>>>(
        projh, combo, Wsc, bHh, ctx_hi, ctx_lo);
    gates_lstm<<<dim3(32,8), 256, 0, stream>>>(
        ctx_hi, ctx_lo, Bih_hi, Bih_lo, combo, WmT, WbT,
        midt, bott, c, hA_hi, hA_lo,
        hid_hi, hid_lo, s);
  }

  // out = hid @ W_gen^T + b_gen  (bf16x2), M = S*B = 13312, N=64 (n<38 kept)
  gemm_bf<64,64,2><<<dim3(1,208), 256, 8192, stream>>>(
      hid_hi, hid_lo, 512, Wg_hi, Wg_lo, 512,
      out, 0, bgen, 3, 16);
}

// Round 13
// 1558.544 us; speedup vs baseline: 1.1659x; 1.1659x over previous
//
#include <hip/hip_runtime.h>
#include <hip/hip_bf16.h>
#include <hip/hip_fp16.h>
#include <cstdint>
#include <cstddef>

#define B_   512
#define T_   128
#define D_   512
#define H_   512
#define MID_ 38
#define BOT_ 38
#define S_   26
#define XL_  588   // D + MID + BOT = W_ih row length

typedef unsigned short u16;
typedef __attribute__((ext_vector_type(8))) short bf16x8v;
typedef __attribute__((ext_vector_type(8))) _Float16 f16x8v;
typedef __attribute__((ext_vector_type(8))) unsigned short u16x8;
typedef __attribute__((ext_vector_type(4))) float f32x4v;

__device__ __forceinline__ u16 f2bf_rn(float f){
  unsigned u = __float_as_uint(f);
  return (u16)((u + 0x7fffu + ((u>>16)&1u)) >> 16);
}
__device__ __forceinline__ float bf2f(u16 v){ return __uint_as_float(((unsigned)v)<<16); }
__device__ __forceinline__ u16 f2h_u(float f){ return __half_as_ushort(__float2half(f)); }
__device__ __forceinline__ float h2f_u(u16 u){ return __half2float(__ushort_as_half(u)); }

// branch-free fast transcendentals (v_exp_f32 + v_rcp_f32, ~1e-6 rel err)
__device__ __forceinline__ float fast_tanh(float x){
  return 1.0f - 2.0f*__builtin_amdgcn_rcpf(__expf(2.0f*x) + 1.0f);
}
__device__ __forceinline__ float fast_sig(float x){
  return __builtin_amdgcn_rcpf(1.0f + __expf(-x));
}

// ---------------------------------------------------------------------------
// One-shot setup: bH->fp16, weight conversions, token tables, bias combine,
// h/c zero-init.  Flat quad-index space, grid-stride.
// ---------------------------------------------------------------------------
__device__ __forceinline__ void cvt_hilo4(const float* src, u16* hi, u16* lo){
  float4 v = *(const float4*)src;
  ushort4 h, l;
  h.x=f2bf_rn(v.x); h.y=f2bf_rn(v.y); h.z=f2bf_rn(v.z); h.w=f2bf_rn(v.w);
  l.x=f2bf_rn(v.x-bf2f(h.x)); l.y=f2bf_rn(v.y-bf2f(h.y));
  l.z=f2bf_rn(v.z-bf2f(h.z)); l.w=f2bf_rn(v.w-bf2f(h.w));
  *(ushort4*)hi = h; *(ushort4*)lo = l;
}

__global__ __launch_bounds__(256) void setup_all(
    const float* __restrict__ bH,
    const float* __restrict__ Wi2h, const float* __restrict__ Wh2h,
    const float* __restrict__ Whh,  const float* __restrict__ Wih,
    const float* __restrict__ Wgen, const float* __restrict__ bh2h,
    const float* __restrict__ bih,  const float* __restrict__ bhh,
    u16* __restrict__ bHh,
    u16* __restrict__ Wi2h_h, u16* __restrict__ Bh2_hi, u16* __restrict__ Bh2_lo,
    u16* __restrict__ Bih_hi, u16* __restrict__ Bih_lo,
    u16* __restrict__ Wg_hi,  u16* __restrict__ Wg_lo,
    float* __restrict__ WmT, float* __restrict__ WbT, float* __restrict__ bcombF,
    u16* __restrict__ hA_hi, u16* __restrict__ hA_lo, float* __restrict__ c)
{
  const int T0 = 8388608;               // bH -> fp16 (65536 rows x 128 quads)
  const int T1 = T0+65536;              // Wi2h -> fp16
  const int T2 = T1+65536;              // Wh2h -> Bh2[0:512] hi/lo
  const int T3 = T2+262144;             // Whh  -> Bh2[512:2560]
  const int T4 = T3+262144;             // Wih[:, :512] -> Bih
  const int T5 = T4+8192;               // Wgen -> Wg (pad 64 rows)
  const int T6 = T5+19456;              // token tables (38*512 quads)
  const int T7 = T6+640;                // bcombF
  const int T8 = T7+65536;              // hA hi/lo zero (ushort4 each)
  const int T9 = T8+65536;              // c zero (float4)
  for (int i = blockIdx.x*256 + threadIdx.x; i < T9; i += gridDim.x*256){
    if (i < T0){
      int row=i>>7, c4=(i&127)*4;
      float4 v = *(const float4*)&bH[(size_t)row*512 + c4];
      ushort4 h; h.x=f2h_u(v.x); h.y=f2h_u(v.y); h.z=f2h_u(v.z); h.w=f2h_u(v.w);
      *(ushort4*)&bHh[(size_t)row*512 + c4] = h;
    } else if (i < T1){
      int j=i-T0, row=j>>7, c4=(j&127)*4;
      float4 v = *(const float4*)&Wi2h[(size_t)row*512 + c4];
      ushort4 h; h.x=f2h_u(v.x); h.y=f2h_u(v.y); h.z=f2h_u(v.z); h.w=f2h_u(v.w);
      *(ushort4*)&Wi2h_h[(size_t)row*512 + c4] = h;
    } else if (i < T2){
      int j=i-T1, row=j>>7, c4=(j&127)*4;
      cvt_hilo4(&Wh2h[(size_t)row*512+c4], &Bh2_hi[(size_t)row*512+c4], &Bh2_lo[(size_t)row*512+c4]);
    } else if (i < T3){
      int j=i-T2, row=j>>7, c4=(j&127)*4;
      cvt_hilo4(&Whh[(size_t)row*512+c4],
                &Bh2_hi[(size_t)(512+row)*512+c4], &Bh2_lo[(size_t)(512+row)*512+c4]);
    } else if (i < T4){
      int j=i-T3, row=j>>7, c4=(j&127)*4;
      cvt_hilo4(&Wih[(size_t)row*XL_+c4], &Bih_hi[(size_t)row*512+c4], &Bih_lo[(size_t)row*512+c4]);
    } else if (i < T5){
      int j=i-T4, row=j>>7, c4=(j&127)*4;
      float4 v = make_float4(0.f,0.f,0.f,0.f);
      if (row < MID_) v = *(const float4*)&Wgen[(size_t)row*512 + c4];
      ushort4 h, l;
      h.x=f2bf_rn(v.x); h.y=f2bf_rn(v.y); h.z=f2bf_rn(v.z); h.w=f2bf_rn(v.w);
      l.x=f2bf_rn(v.x-bf2f(h.x)); l.y=f2bf_rn(v.y-bf2f(h.y));
      l.z=f2bf_rn(v.z-bf2f(h.z)); l.w=f2bf_rn(v.w-bf2f(h.w));
      *(ushort4*)&Wg_hi[(size_t)row*512+c4] = h;
      *(ushort4*)&Wg_lo[(size_t)row*512+c4] = l;
    } else if (i < T6){
      int j=i-T5;                    // 38*512
      int cc=j>>9, jq=j&511;
#pragma unroll
      for (int u=0;u<4;u++){
        int jj=jq*4+u;
        WmT[(size_t)cc*2048+jj] = Wih[(size_t)jj*XL_ + 512 + cc];
        WbT[(size_t)cc*2048+jj] = Wih[(size_t)jj*XL_ + 512 + MID_ + cc];
      }
    } else if (i < T7){
      int j=(i-T6)*4;
#pragma unroll
      for (int u=0;u<4;u++){
        int k=j+u;
        if (k < 512) bcombF[k] = bh2h[k];
        else if (k < 2560) bcombF[k] = bih[k-512] + bhh[k-512];
      }
    } else if (i < T8){
      int j=i-T7;
      ushort4 z = {0,0,0,0};
      *(ushort4*)&hA_hi[(size_t)j*4] = z;
      *(ushort4*)&hA_lo[(size_t)j*4] = z;
    } else {
      int j=i-T8;
      *(float4*)&c[(size_t)j*4] = make_float4(0.f,0.f,0.f,0.f);
    }
  }
}

// ---------------------------------------------------------------------------
// proj GEMM, pure fp16, BM=BN=128, XCD-aware 1D grid (2048 blocks),
// reg-staged with 1-ahead prefetch (R11-proven).
// A = bHh fp16, B = Wi2h fp16.  C = fp16 projh via LDS bounce.
// ---------------------------------------------------------------------------
__global__ __launch_bounds__(256) void gemm_proj16(
    const u16* __restrict__ Ah, const u16* __restrict__ Bh,
    u16* __restrict__ projh)
{
  extern __shared__ char smem[];
  constexpr int STR = 40;
  short* As = (short*)smem;                  // [128][STR]
  short* Bs = As + 128*STR;
  const int tid=threadIdx.x;
  const int n = blockIdx.x;
  const int x = n & 7, q = n >> 3;
  const int bn = (q & 3) * 128;
  const int bm = ((q >> 2)*8 + x) * 128;
  const int w=tid>>6, lane=tid&63, wr=w>>1, wc=w&1;

  f32x4v acc[4][4];
#pragma unroll
  for (int i=0;i<4;i++)
#pragma unroll
    for (int j=0;j<4;j++) acc[i][j] = (f32x4v){0.f,0.f,0.f,0.f};

  u16x8 ra[2], rb[2];
  auto load = [&](int it){
    const int kk = it<<5;
#pragma unroll
    for (int L=0; L<2; L++){
      int t=L*256+tid, row=t>>2, c=(t&3)*8;
      ra[L] = *(const u16x8*)&Ah[(size_t)(bm+row)*512 + kk + c];
      rb[L] = *(const u16x8*)&Bh[(size_t)(bn+row)*512 + kk + c];
    }
  };
  load(0);

  for (int it=0; it<16; ++it){
    __syncthreads();
#pragma unroll
    for (int L=0; L<2; L++){
      int t=L*256+tid, row=t>>2, c=(t&3)*8;
      *(u16x8*)&As[row*STR+c] = ra[L];
      *(u16x8*)&Bs[row*STR+c] = rb[L];
    }
    if (it+1 < 16) load(it+1);
    __syncthreads();
    const int koff = (lane>>4)*8, mrow = lane&15;
#pragma unroll
    for (int i=0;i<4;i++)
#pragma unroll
      for (int j=0;j<4;j++){
        f16x8v af = *(const f16x8v*)&As[(wr*64+i*16+mrow)*STR + koff];
        f16x8v bf = *(const f16x8v*)&Bs[(wc*64+j*16+mrow)*STR + koff];
        acc[i][j] = __builtin_amdgcn_mfma_f32_16x16x32_f16(af, bf, acc[i][j], 0,0,0);
      }
  }

  // epilogue: fp16 out via LDS bounce
  const int r0 = (lane>>4)*4, cn = lane&15;
  __syncthreads();
  u16* Ts = (u16*)smem;   // [128][128]
#pragma unroll
  for (int i=0;i<4;i++)
#pragma unroll
    for (int j=0;j<4;j++)
#pragma unroll
      for (int r=0;r<4;r++)
        Ts[(wr*64+i*16+r0+r)*128 + wc*64+j*16+cn] = f2h_u(acc[i][j][r]);
  __syncthreads();
#pragma unroll
  for (int q2=0;q2<8;q2++){
    int idx = q2*256 + tid;
    int row = idx>>4, c8 = (idx&15)*8;
    *(float4*)&projh[(size_t)(bm+row)*512 + bn + c8] = *(const float4*)&Ts[row*128 + c8];
  }
}

// ---------------------------------------------------------------------------
// bf16 MFMA GEMM 64x64, K=512, bf16x2 3-pass, BK=64, STR=72 pad,
// a0/a1 register ping-pong with 1-ahead prefetch (gates_lstm-proven loop).
// MODE 0: fp32 out + col-bias.  MODE 2: generator out (m->(s,b), n<38, +bias2).
// ---------------------------------------------------------------------------
template<int MODE>
__global__ __launch_bounds__(256) void gemm_bf64(
    const u16* __restrict__ Ah, const u16* __restrict__ Al, int lda,
    const u16* __restrict__ Bh, const u16* __restrict__ Bl, int ldb,
    float* __restrict__ Cout, int ldc, const float* __restrict__ bias2)
{
  constexpr int STR = 72;                  // 64 + 8 pad (2-way read, free)
  __shared__ short As[64*STR];
  __shared__ short Bs[64*STR];
  const int tid=threadIdx.x, lane=tid&63, w=tid>>6, wr=w>>1, wc=w&1;
  const int bm=blockIdx.y*64, bn=blockIdx.x*64;
  const int mrow=lane&15, koff=(lane>>4)*8;
  const int srow=tid>>2, scc=(tid&3)*8;

  f32x4v acc[2][2];
#pragma unroll
  for (int i=0;i<2;i++)
#pragma unroll
    for (int j=0;j<2;j++) acc[i][j] = (f32x4v){0.f,0.f,0.f,0.f};

  u16x8 sa0[2], sb0[2], sa1[2], sb1[2];
  auto load0 = [&](int it){
    const int pass = it>>3, kk=(it&7)<<6;
    const u16* Ap = (pass==2)?Al:Ah;
    const u16* Bp = (pass==1)?Bl:Bh;
    sa0[0] = *(const u16x8*)&Ap[(size_t)(bm+srow)*lda + kk + scc];
    sa0[1] = *(const u16x8*)&Ap[(size_t)(bm+srow)*lda + kk + scc + 32];
    sb0[0] = *(const u16x8*)&Bp[(size_t)(bn+srow)*ldb + kk + scc];
    sb0[1] = *(const u16x8*)&Bp[(size_t)(bn+srow)*ldb + kk + scc + 32];
  };
  auto load1 = [&](int it){
    const int pass = it>>3, kk=(it&7)<<6;
    const u16* Ap = (pass==2)?Al:Ah;
    const u16* Bp = (pass==1)?Bl:Bh;
    sa1[0] = *(const u16x8*)&Ap[(size_t)(bm+srow)*lda + kk + scc];
    sa1[1] = *(const u16x8*)&Ap[(size_t)(bm+srow)*lda + kk + scc + 32];
    sb1[0] = *(const u16x8*)&Bp[(size_t)(bn+srow)*ldb + kk + scc];
    sb1[1] = *(const u16x8*)&Bp[(size_t)(bn+srow)*ldb + kk + scc + 32];
  };

  load0(0);
  for (int it=0; it<24; it+=2){
    __syncthreads();
    *(u16x8*)&As[srow*STR+scc]    = sa0[0];
    *(u16x8*)&As[srow*STR+scc+32] = sa0[1];
    *(u16x8*)&Bs[srow*STR+scc]    = sb0[0];
    *(u16x8*)&Bs[srow*STR+scc+32] = sb0[1];
    if (it+1 < 24) load1(it+1);
    __syncthreads();
#pragma unroll
    for (int i=0;i<2;i++)
#pragma unroll
      for (int j=0;j<2;j++)
#pragma unroll
        for (int ks=0;ks<2;ks++){
          bf16x8v af = *(const bf16x8v*)&As[(wr*32+i*16+mrow)*STR + ks*32 + koff];
          bf16x8v bf = *(const bf16x8v*)&Bs[(wc*32+j*16+mrow)*STR + ks*32 + koff];
          acc[i][j] = __builtin_amdgcn_mfma_f32_16x16x32_bf16(af, bf, acc[i][j], 0,0,0);
        }
    if (it+1 >= 24) break;
    __syncthreads();
    *(u16x8*)&As[srow*STR+scc]    = sa1[0];
    *(u16x8*)&As[srow*STR+scc+32] = sa1[1];
    *(u16x8*)&Bs[srow*STR+scc]    = sb1[0];
    *(u16x8*)&Bs[srow*STR+scc+32] = sb1[1];
    if (it+2 < 24) load0(it+2);
    __syncthreads();
#pragma unroll
    for (int i=0;i<2;i++)
#pragma unroll
      for (int j=0;j<2;j++)
#pragma unroll
        for (int ks=0;ks<2;ks++){
          bf16x8v af = *(const bf16x8v*)&As[(wr*32+i*16+mrow)*STR + ks*32 + koff];
          bf16x8v bf = *(const bf16x8v*)&Bs[(wc*32+j*16+mrow)*STR + ks*32 + koff];
          acc[i][j] = __builtin_amdgcn_mfma_f32_16x16x32_bf16(af, bf, acc[i][j], 0,0,0);
        }
  }

  const int r0 = (lane>>4)*4, cn = lane&15;
  if constexpr (MODE==2){
#pragma unroll
    for (int i=0;i<2;i++)
#pragma unroll
      for (int j=0;j<2;j++)
#pragma unroll
        for (int r=0;r<4;r++){
          int m = bm + wr*32 + i*16 + r0 + r;       // m = s*512 + b
          int n2 = bn + wc*32 + j*16 + cn;
          if (n2 < MID_){
            int s = m >> 9, b = m & 511;
            Cout[((size_t)b*S_ + s)*MID_ + n2] = acc[i][j][r] + bias2[n2];
          }
        }
  } else {
#pragma unroll
    for (int i=0;i<2;i++)
#pragma unroll
      for (int j=0;j<2;j++)
#pragma unroll
        for (int r=0;r<4;r++){
          int row = bm + wr*32 + i*16 + r0 + r;
          int col = bn + wc*32 + j*16 + cn;
          float v = acc[i][j][r];
          if (bias2) v += bias2[col];
          Cout[(size_t)row*ldc + col] = v;
        }
  }
}

// ---------------------------------------------------------------------------
// Fused attention, 1024 threads (16 waves)  (R11-proven version):
//   pp from combo[b][0:512] (fp32, ld 2560)
//   e[t] = sum_h Ws[h]*fast_tanh(projh[b,t,h]+pp[h]); softmax over t;
//   ctx[b,d] = sum_t alpha[t]*bHh[b,t,d] -> ctx hi/lo planes.
// ---------------------------------------------------------------------------
__global__ __launch_bounds__(1024) void attn_kernel(
    const u16* __restrict__ projh, const float* __restrict__ combo,
    const float* __restrict__ Wscore, const u16* __restrict__ bHh,
    u16* __restrict__ ctx_hi, u16* __restrict__ ctx_lo)
{
  __shared__ float s_e[T_];
  __shared__ float s_red[32];
  __shared__ float s_part[16][D_];
  const int tid=threadIdx.x, b=blockIdx.x, wave=tid>>6, lane=tid&63;

  float pv[8], wv[8];
  {
    const float* pprow = combo + (size_t)b*2560;
    float4 p0=*(const float4*)&pprow[lane*8], p1=*(const float4*)&pprow[lane*8+4];
    float4 w0=*(const float4*)&Wscore[lane*8], w1=*(const float4*)&Wscore[lane*8+4];
    pv[0]=p0.x;pv[1]=p0.y;pv[2]=p0.z;pv[3]=p0.w;pv[4]=p1.x;pv[5]=p1.y;pv[6]=p1.z;pv[7]=p1.w;
    wv[0]=w0.x;wv[1]=w0.y;wv[2]=w0.z;wv[3]=w0.w;wv[4]=w1.x;wv[5]=w1.y;wv[6]=w1.z;wv[7]=w1.w;
  }
  // e-phase: wave w handles t = w, w+16, ... (8 rows); 2-deep pipeline
  {
    const u16* base = projh + (size_t)b*T_*H_ + lane*8;
    u16x8 cur = *(const u16x8*)(base + (size_t)wave*H_);
    for (int t=wave; t<T_; t+=16){
      u16x8 nxt;
      if (t+16 < T_) nxt = *(const u16x8*)(base + (size_t)(t+16)*H_);
      float acc = 0.f;
#pragma unroll
      for (int j=0;j<8;j++) acc += wv[j]*fast_tanh(h2f_u(cur[j]) + pv[j]);
#pragma unroll
      for (int o=32;o>0;o>>=1) acc += __shfl_down(acc,o);
      if (lane==0) s_e[t] = acc;
      cur = nxt;
    }
  }
  __syncthreads();
  // softmax over s_e[0..127]
  float v = (tid < T_) ? s_e[tid] : -INFINITY;
  float m = v;
#pragma unroll
  for (int o=32;o>0;o>>=1) m = fmaxf(m, __shfl_down(m,o));
  if (tid < T_ && lane==0) s_red[wave] = m;      // waves 0,1 write
  __syncthreads();
  m = fmaxf(s_red[0], s_red[1]);
  float p = (tid < T_) ? __expf(v - m) : 0.f;
  float sum = p;
#pragma unroll
  for (int o=32;o>0;o>>=1) sum += __shfl_down(sum,o);
  if (tid < T_ && lane==0) s_red[16+wave] = sum;
  __syncthreads();
  float denom = s_red[16] + s_red[17];
  if (tid < T_) s_e[tid] = p/denom;
  __syncthreads();

  // context: wave w covers t in [8w, 8w+8); lane covers d = lane*8..+7
  const int d0 = lane*8;
  float a[8] = {0,0,0,0,0,0,0,0};
  {
    const u16* base = bHh + (size_t)b*T_*D_ + d0;
    u16x8 cur = *(const u16x8*)(base + (size_t)(wave*8)*D_);
    for (int t=wave*8; t<wave*8+8; ++t){
      u16x8 nxt;
      if (t+1 < wave*8+8) nxt = *(const u16x8*)(base + (size_t)(t+1)*D_);
      const float al = s_e[t];
#pragma unroll
      for (int j=0;j<8;j++) a[j] += al*h2f_u(cur[j]);
      cur = nxt;
    }
  }
  *(float4*)&s_part[wave][d0]   = make_float4(a[0],a[1],a[2],a[3]);
  *(float4*)&s_part[wave][d0+4] = make_float4(a[4],a[5],a[6],a[7]);
  __syncthreads();
  if (tid < D_){
    float vv = s_part[0][tid];
#pragma unroll
    for (int q=1;q<16;q++) vv += s_part[q][tid];
    u16 hh=f2bf_rn(vv), ll=f2bf_rn(vv-bf2f(hh));
    ctx_hi[(size_t)b*512 + tid] = hh;
    ctx_lo[(size_t)b*512 + tid] = ll;
  }
}

// ---------------------------------------------------------------------------
// Fused gates GEMM + LSTM pointwise (unchanged, proven).  K=512 bf16x2
// 3-pass, BK=64.  gates = ctx @ W_ih[:,:512]^T + combo[:,512:].
// ---------------------------------------------------------------------------
__global__ __launch_bounds__(256) void gates_lstm(
    const u16* __restrict__ Ah, const u16* __restrict__ Al,     // [512][512]
    const u16* __restrict__ Bh, const u16* __restrict__ Bl,     // [2048][512]
    const float* __restrict__ combo,                            // [512][2560]
    const float* __restrict__ WmT, const float* __restrict__ WbT,
    const int* __restrict__ midtok, const int* __restrict__ bottok,
    float* __restrict__ c,
    u16* __restrict__ hA_hi, u16* __restrict__ hA_lo,
    u16* __restrict__ hid_hi, u16* __restrict__ hid_lo, int s)
{
  constexpr int STR = 72;
  __shared__ short Bs[64*STR];
  const int tid=threadIdx.x, lane=tid&63, w=tid>>6;
  const int j0 = blockIdx.x*16, bm = blockIdx.y*64;
  const int mrow=lane&15, koff=(lane>>4)*8;
  const int arow = bm + w*16 + mrow;
  const int srow = tid>>2, scc=(tid&3)*8;
  const int sbrow = (srow>>4)*512 + j0 + (srow&15);

  f32x4v acc[4];
#pragma unroll
  for (int f=0;f<4;f++) acc[f] = (f32x4v){0.f,0.f,0.f,0.f};

  u16x8 sb0, sb1;
  bf16x8v a0[2], a1[2];
  auto loadB = [&](int it){
    const int pass = it>>3, kk=(it&7)<<6;
    const u16* Bp = (pass==1)?Bl:Bh;
    sb0 = *(const u16x8*)&Bp[(size_t)sbrow*512 + kk + scc];
    sb1 = *(const u16x8*)&Bp[(size_t)sbrow*512 + kk + scc + 32];
  };
  auto loadA0 = [&](int it){
    const int pass = it>>3, kk=(it&7)<<6;
    const u16* Ap = (pass==2)?Al:Ah;
    a0[0] = *(const bf16x8v*)&Ap[(size_t)arow*512 + kk + koff];
    a0[1] = *(const bf16x8v*)&Ap[(size_t)arow*512 + kk + koff + 32];
  };
  auto loadA1 = [&](int it){
    const int pass = it>>3, kk=(it&7)<<6;
    const u16* Ap = (pass==2)?Al:Ah;
    a1[0] = *(const bf16x8v*)&Ap[(size_t)arow*512 + kk + koff];
    a1[1] = *(const bf16x8v*)&Ap[(size_t)arow*512 + kk + koff + 32];
  };

  loadB(0); loadA0(0);
  for (int it=0; it<24; it+=2){
    __syncthreads();
    *(u16x8*)&Bs[srow*STR+scc]    = sb0;
    *(u16x8*)&Bs[srow*STR+scc+32] = sb1;
    if (it+1 < 24){ loadB(it+1); loadA1(it+1); }
    __syncthreads();
#pragma unroll
    for (int f=0;f<4;f++){
      bf16x8v b0 = *(const bf16x8v*)&Bs[(f*16+mrow)*STR + koff];
      bf16x8v b1 = *(const bf16x8v*)&Bs[(f*16+mrow)*STR + koff + 32];
      acc[f] = __builtin_amdgcn_mfma_f32_16x16x32_bf16(a0[0], b0, acc[f], 0,0,0);
      acc[f] = __builtin_amdgcn_mfma_f32_16x16x32_bf16(a0[1], b1, acc[f], 0,0,0);
    }
    if (it+1 >= 24) break;
    __syncthreads();
    *(u16x8*)&Bs[srow*STR+scc]    = sb0;
    *(u16x8*)&Bs[srow*STR+scc+32] = sb1;
    if (it+2 < 24){ loadB(it+2); loadA0(it+2); }
    __syncthreads();
#pragma unroll
    for (int f=0;f<4;f++){
      bf16x8v b0 = *(const bf16x8v*)&Bs[(f*16+mrow)*STR + koff];
      bf16x8v b1 = *(const bf16x8v*)&Bs[(f*16+mrow)*STR + koff + 32];
      acc[f] = __builtin_amdgcn_mfma_f32_16x16x32_bf16(a1[0], b0, acc[f], 0,0,0);
      acc[f] = __builtin_amdgcn_mfma_f32_16x16x32_bf16(a1[1], b1, acc[f], 0,0,0);
    }
  }

  // epilogue: lane holds gates f=0..3 for rows r0..r0+3 (b), col jj
  const int r0=(lane>>4)*4, jj=lane&15, j=j0+jj;
#pragma unroll
  for (int r=0;r<4;r++){
    const int b = bm + w*16 + r0 + r;
    const int mt = midtok[b*26 + s];
    const int bt = bottok[b*26 + s];
    const float* wm = WmT + (size_t)mt*2048;
    const float* wb = WbT + (size_t)bt*2048;
    const float* cb = combo + (size_t)b*2560 + 512;
    float ig = acc[0][r] + cb[j       ] + wm[j       ] + wb[j       ];
    float fg = acc[1][r] + cb[512 + j ] + wm[512 + j ] + wb[512 + j ];
    float gg = acc[2][r] + cb[1024 + j] + wm[1024 + j] + wb[1024 + j];
    float og = acc[3][r] + cb[1536 + j] + wm[1536 + j] + wb[1536 + j];
    ig = fast_sig(ig);
    fg = fast_sig(fg);
    gg = fast_tanh(gg);
    og = fast_sig(og);
    const size_t ci = (size_t)b*512 + j;
    const float cn = fg*c[ci] + ig*gg;
    const float hn = og*fast_tanh(cn);
    c[ci] = cn;
    u16 hh = f2bf_rn(hn), hl = f2bf_rn(hn - bf2f(hh));
    hA_hi[ci] = hh;
    hA_lo[ci] = hl;
    hid_hi[((size_t)s*512 + b)*512 + j] = hh;
    hid_lo[((size_t)s*512 + b)*512 + j] = hl;
  }
}

extern "C" void kernel_launch(void* const* d_in, const int* in_sizes, int n_in,
                              void* d_out, int out_size, void* d_ws, size_t ws_size,
                              hipStream_t stream) {
  const float* bH   = (const float*)d_in[0];
  const int*   midt = (const int*)  d_in[1];
  const int*   bott = (const int*)  d_in[2];
  const float* Wi2h = (const float*)d_in[3];
  const float* Wh2h = (const float*)d_in[4];
  const float* bh2h = (const float*)d_in[5];
  const float* Wsc  = (const float*)d_in[6];
  const float* Wih  = (const float*)d_in[7];
  const float* Whh  = (const float*)d_in[8];
  const float* bih  = (const float*)d_in[9];
  const float* bhh  = (const float*)d_in[10];
  const float* Wgen = (const float*)d_in[11];
  const float* bgen = (const float*)d_in[12];
  float* out = (float*)d_out;

  char* wp = (char*)d_ws;
  u16* projh   = (u16*)wp; wp += (size_t)B_*T_*H_*2;      // 67.1 MB fp16
  u16* bHh     = (u16*)wp; wp += (size_t)B_*T_*D_*2;      // 67.1 MB fp16
  u16* Bh2_hi  = (u16*)wp; wp += (size_t)2560*512*2;      // [W_h2h|W_hh] planes
  u16* Bh2_lo  = (u16*)wp; wp += (size_t)2560*512*2;
  u16* Bih_hi  = (u16*)wp; wp += (size_t)2048*512*2;      // W_ih[:, :512] planes
  u16* Bih_lo  = (u16*)wp; wp += (size_t)2048*512*2;
  u16* Wi2h_h  = (u16*)wp; wp += (size_t)512*512*2;       // fp16
  u16* Wg_hi   = (u16*)wp; wp += (size_t)64*512*2;
  u16* Wg_lo   = (u16*)wp; wp += (size_t)64*512*2;
  u16* ctx_hi  = (u16*)wp; wp += (size_t)B_*512*2;
  u16* ctx_lo  = (u16*)wp; wp += (size_t)B_*512*2;
  u16* hA_hi   = (u16*)wp; wp += (size_t)B_*512*2;
  u16* hA_lo   = (u16*)wp; wp += (size_t)B_*512*2;
  u16* hid_hi  = (u16*)wp; wp += (size_t)S_*B_*H_*2;      // 13.6 MB
  u16* hid_lo  = (u16*)wp; wp += (size_t)S_*B_*H_*2;
  float* combo = (float*)wp; wp += (size_t)B_*2560*4;     // 5.2 MB
  float* c     = (float*)wp; wp += (size_t)B_*H_*4;
  float* bcombF= (float*)wp; wp += (size_t)2560*4;
  float* WmT   = (float*)wp; wp += (size_t)MID_*2048*4;
  float* WbT   = (float*)wp; wp += (size_t)BOT_*2048*4;
  if ((size_t)(wp - (char*)d_ws) > ws_size) return;  // fail loudly

  setup_all<<<4096, 256, 0, stream>>>(
      bH, Wi2h, Wh2h, Whh, Wih, Wgen, bh2h, bih, bhh,
      bHh, Wi2h_h, Bh2_hi, Bh2_lo, Bih_hi, Bih_lo, Wg_hi, Wg_lo,
      WmT, WbT, bcombF, hA_hi, hA_lo, c);

  // proj = fp16( bHh @ Wi2h^T ), pure fp16, XCD-aware 1D grid
  gemm_proj16<<<2048, 256, 32768, stream>>>(bHh, Wi2h_h, projh);

  for (int s=0; s<S_; ++s){
    // combo = h @ [W_h2h | W_hh]^T + [b_h2h | b_ih+b_hh]  (bf16x2, BK=64)
    gemm_bf64<0><<<dim3(40,8), 256, 0, stream>>>(
        hA_hi, hA_lo, 512, Bh2_hi, Bh2_lo, 512,
        combo, 2560, bcombF);
    attn_kernel<<<B_, 1024, 0, stream>>>(
        projh, combo, Wsc, bHh, ctx_hi, ctx_lo);
    gates_lstm<<<dim3(32,8), 256, 0, stream>>>(
        ctx_hi, ctx_lo, Bih_hi, Bih_lo, combo, WmT, WbT,
        midt, bott, c, hA_hi, hA_lo,
        hid_hi, hid_lo, s);
  }

  // out = hid @ W_gen^T + b_gen  (bf16x2, BK=64), M = S*B = 13312
  gemm_bf64<2><<<dim3(1,208), 256, 0, stream>>>(
      hid_hi, hid_lo, 512, Wg_hi, Wg_lo, 512,
      out, 0, bgen);
}

// Round 14
// 1544.078 us; speedup vs baseline: 1.1768x; 1.0094x over previous
//
#include <hip/hip_runtime.h>
#include <hip/hip_bf16.h>
#include <hip/hip_fp16.h>
#include <cstdint>
#include <cstddef>

#define B_   512
#define T_   128
#define D_   512
#define H_   512
#define MID_ 38
#define BOT_ 38
#define S_   26
#define XL_  588   // D + MID + BOT = W_ih row length

typedef unsigned short u16;
typedef __attribute__((ext_vector_type(8))) short bf16x8v;
typedef __attribute__((ext_vector_type(8))) _Float16 f16x8v;
typedef __attribute__((ext_vector_type(8))) unsigned short u16x8;
typedef __attribute__((ext_vector_type(4))) float f32x4v;

__device__ __forceinline__ u16 f2bf_rn(float f){
  unsigned u = __float_as_uint(f);
  return (u16)((u + 0x7fffu + ((u>>16)&1u)) >> 16);
}
__device__ __forceinline__ float bf2f(u16 v){ return __uint_as_float(((unsigned)v)<<16); }
__device__ __forceinline__ u16 f2h_u(float f){ return __half_as_ushort(__float2half(f)); }
__device__ __forceinline__ float h2f_u(u16 u){ return __half2float(__ushort_as_half(u)); }

// branch-free fast transcendentals (v_exp_f32 + v_rcp_f32, ~1e-6 rel err)
__device__ __forceinline__ float fast_tanh(float x){
  return 1.0f - 2.0f*__builtin_amdgcn_rcpf(__expf(2.0f*x) + 1.0f);
}
__device__ __forceinline__ float fast_sig(float x){
  return __builtin_amdgcn_rcpf(1.0f + __expf(-x));
}

// ---------------------------------------------------------------------------
// One-shot setup: bH->fp16, weight conversions, token tables, bias combine,
// h/c zero-init.  Flat quad-index space, grid-stride.
// ---------------------------------------------------------------------------
__device__ __forceinline__ void cvt_hilo4(const float* src, u16* hi, u16* lo){
  float4 v = *(const float4*)src;
  ushort4 h, l;
  h.x=f2bf_rn(v.x); h.y=f2bf_rn(v.y); h.z=f2bf_rn(v.z); h.w=f2bf_rn(v.w);
  l.x=f2bf_rn(v.x-bf2f(h.x)); l.y=f2bf_rn(v.y-bf2f(h.y));
  l.z=f2bf_rn(v.z-bf2f(h.z)); l.w=f2bf_rn(v.w-bf2f(h.w));
  *(ushort4*)hi = h; *(ushort4*)lo = l;
}

__global__ __launch_bounds__(256) void setup_all(
    const float* __restrict__ bH,
    const float* __restrict__ Wi2h, const float* __restrict__ Wh2h,
    const float* __restrict__ Whh,  const float* __restrict__ Wih,
    const float* __restrict__ Wgen, const float* __restrict__ bh2h,
    const float* __restrict__ bih,  const float* __restrict__ bhh,
    u16* __restrict__ bHh,
    u16* __restrict__ Wi2h_h, u16* __restrict__ Bh2_hi, u16* __restrict__ Bh2_lo,
    u16* __restrict__ Bih_hi, u16* __restrict__ Bih_lo,
    u16* __restrict__ Wg_hi,  u16* __restrict__ Wg_lo,
    float* __restrict__ WmT, float* __restrict__ WbT, float* __restrict__ bcombF,
    u16* __restrict__ hA_hi, u16* __restrict__ hA_lo, float* __restrict__ c)
{
  const int T0 = 8388608;               // bH -> fp16 (65536 rows x 128 quads)
  const int T1 = T0+65536;              // Wi2h -> fp16
  const int T2 = T1+65536;              // Wh2h -> Bh2[0:512] hi/lo
  const int T3 = T2+262144;             // Whh  -> Bh2[512:2560]
  const int T4 = T3+262144;             // Wih[:, :512] -> Bih
  const int T5 = T4+8192;               // Wgen -> Wg (pad 64 rows)
  const int T6 = T5+19456;              // token tables (38*512 quads)
  const int T7 = T6+640;                // bcombF
  const int T8 = T7+65536;              // hA hi/lo zero (ushort4 each)
  const int T9 = T8+65536;              // c zero (float4)
  for (int i = blockIdx.x*256 + threadIdx.x; i < T9; i += gridDim.x*256){
    if (i < T0){
      int row=i>>7, c4=(i&127)*4;
      float4 v = *(const float4*)&bH[(size_t)row*512 + c4];
      ushort4 h; h.x=f2h_u(v.x); h.y=f2h_u(v.y); h.z=f2h_u(v.z); h.w=f2h_u(v.w);
      *(ushort4*)&bHh[(size_t)row*512 + c4] = h;
    } else if (i < T1){
      int j=i-T0, row=j>>7, c4=(j&127)*4;
      float4 v = *(const float4*)&Wi2h[(size_t)row*512 + c4];
      ushort4 h; h.x=f2h_u(v.x); h.y=f2h_u(v.y); h.z=f2h_u(v.z); h.w=f2h_u(v.w);
      *(ushort4*)&Wi2h_h[(size_t)row*512 + c4] = h;
    } else if (i < T2){
      int j=i-T1, row=j>>7, c4=(j&127)*4;
      cvt_hilo4(&Wh2h[(size_t)row*512+c4], &Bh2_hi[(size_t)row*512+c4], &Bh2_lo[(size_t)row*512+c4]);
    } else if (i < T3){
      int j=i-T2, row=j>>7, c4=(j&127)*4;
      cvt_hilo4(&Whh[(size_t)row*512+c4],
                &Bh2_hi[(size_t)(512+row)*512+c4], &Bh2_lo[(size_t)(512+row)*512+c4]);
    } else if (i < T4){
      int j=i-T3, row=j>>7, c4=(j&127)*4;
      cvt_hilo4(&Wih[(size_t)row*XL_+c4], &Bih_hi[(size_t)row*512+c4], &Bih_lo[(size_t)row*512+c4]);
    } else if (i < T5){
      int j=i-T4, row=j>>7, c4=(j&127)*4;
      float4 v = make_float4(0.f,0.f,0.f,0.f);
      if (row < MID_) v = *(const float4*)&Wgen[(size_t)row*512 + c4];
      ushort4 h, l;
      h.x=f2bf_rn(v.x); h.y=f2bf_rn(v.y); h.z=f2bf_rn(v.z); h.w=f2bf_rn(v.w);
      l.x=f2bf_rn(v.x-bf2f(h.x)); l.y=f2bf_rn(v.y-bf2f(h.y));
      l.z=f2bf_rn(v.z-bf2f(h.z)); l.w=f2bf_rn(v.w-bf2f(h.w));
      *(ushort4*)&Wg_hi[(size_t)row*512+c4] = h;
      *(ushort4*)&Wg_lo[(size_t)row*512+c4] = l;
    } else if (i < T6){
      int j=i-T5;                    // 38*512
      int cc=j>>9, jq=j&511;
#pragma unroll
      for (int u=0;u<4;u++){
        int jj=jq*4+u;
        WmT[(size_t)cc*2048+jj] = Wih[(size_t)jj*XL_ + 512 + cc];
        WbT[(size_t)cc*2048+jj] = Wih[(size_t)jj*XL_ + 512 + MID_ + cc];
      }
    } else if (i < T7){
      int j=(i-T6)*4;
#pragma unroll
      for (int u=0;u<4;u++){
        int k=j+u;
        if (k < 512) bcombF[k] = bh2h[k];
        else if (k < 2560) bcombF[k] = bih[k-512] + bhh[k-512];
      }
    } else if (i < T8){
      int j=i-T7;
      ushort4 z = {0,0,0,0};
      *(ushort4*)&hA_hi[(size_t)j*4] = z;
      *(ushort4*)&hA_lo[(size_t)j*4] = z;
    } else {
      int j=i-T8;
      *(float4*)&c[(size_t)j*4] = make_float4(0.f,0.f,0.f,0.f);
    }
  }
}

// ---------------------------------------------------------------------------
// proj GEMM, pure fp16, BM=BN=128, XCD-aware 1D grid (2048 blocks),
// reg-staged with 1-ahead prefetch (R11-proven).
// A = bHh fp16, B = Wi2h fp16.  C = fp16 projh via LDS bounce.
// ---------------------------------------------------------------------------
__global__ __launch_bounds__(256) void gemm_proj16(
    const u16* __restrict__ Ah, const u16* __restrict__ Bh,
    u16* __restrict__ projh)
{
  extern __shared__ char smem[];
  constexpr int STR = 40;
  short* As = (short*)smem;                  // [128][STR]
  short* Bs = As + 128*STR;
  const int tid=threadIdx.x;
  const int n = blockIdx.x;
  const int x = n & 7, q = n >> 3;
  const int bn = (q & 3) * 128;
  const int bm = ((q >> 2)*8 + x) * 128;
  const int w=tid>>6, lane=tid&63, wr=w>>1, wc=w&1;

  f32x4v acc[4][4];
#pragma unroll
  for (int i=0;i<4;i++)
#pragma unroll
    for (int j=0;j<4;j++) acc[i][j] = (f32x4v){0.f,0.f,0.f,0.f};

  u16x8 ra[2], rb[2];
  auto load = [&](int it){
    const int kk = it<<5;
#pragma unroll
    for (int L=0; L<2; L++){
      int t=L*256+tid, row=t>>2, c=(t&3)*8;
      ra[L] = *(const u16x8*)&Ah[(size_t)(bm+row)*512 + kk + c];
      rb[L] = *(const u16x8*)&Bh[(size_t)(bn+row)*512 + kk + c];
    }
  };
  load(0);

  for (int it=0; it<16; ++it){
    __syncthreads();
#pragma unroll
    for (int L=0; L<2; L++){
      int t=L*256+tid, row=t>>2, c=(t&3)*8;
      *(u16x8*)&As[row*STR+c] = ra[L];
      *(u16x8*)&Bs[row*STR+c] = rb[L];
    }
    if (it+1 < 16) load(it+1);
    __syncthreads();
    const int koff = (lane>>4)*8, mrow = lane&15;
#pragma unroll
    for (int i=0;i<4;i++)
#pragma unroll
      for (int j=0;j<4;j++){
        f16x8v af = *(const f16x8v*)&As[(wr*64+i*16+mrow)*STR + koff];
        f16x8v bf = *(const f16x8v*)&Bs[(wc*64+j*16+mrow)*STR + koff];
        acc[i][j] = __builtin_amdgcn_mfma_f32_16x16x32_f16(af, bf, acc[i][j], 0,0,0);
      }
  }

  // epilogue: fp16 out via LDS bounce
  const int r0 = (lane>>4)*4, cn = lane&15;
  __syncthreads();
  u16* Ts = (u16*)smem;   // [128][128]
#pragma unroll
  for (int i=0;i<4;i++)
#pragma unroll
    for (int j=0;j<4;j++)
#pragma unroll
      for (int r=0;r<4;r++)
        Ts[(wr*64+i*16+r0+r)*128 + wc*64+j*16+cn] = f2h_u(acc[i][j][r]);
  __syncthreads();
#pragma unroll
  for (int q2=0;q2<8;q2++){
    int idx = q2*256 + tid;
    int row = idx>>4, c8 = (idx&15)*8;
    *(float4*)&projh[(size_t)(bm+row)*512 + bn + c8] = *(const float4*)&Ts[row*128 + c8];
  }
}

// ---------------------------------------------------------------------------
// bf16 MFMA GEMM 64x64, K=512, bf16x2 3-pass, BK=64, STR=72 pad,
// register ping-pong with 1-ahead prefetch (gates_lstm-proven loop).
// MODE 0: fp32 out + col-bias.  MODE 2: generator out (m->(s,b), n<38, +bias2).
// ---------------------------------------------------------------------------
template<int MODE>
__global__ __launch_bounds__(256) void gemm_bf64(
    const u16* __restrict__ Ah, const u16* __restrict__ Al, int lda,
    const u16* __restrict__ Bh, const u16* __restrict__ Bl, int ldb,
    float* __restrict__ Cout, int ldc, const float* __restrict__ bias2)
{
  constexpr int STR = 72;                  // 64 + 8 pad (2-way read, free)
  __shared__ short As[64*STR];
  __shared__ short Bs[64*STR];
  const int tid=threadIdx.x, lane=tid&63, w=tid>>6, wr=w>>1, wc=w&1;
  const int bm=blockIdx.y*64, bn=blockIdx.x*64;
  const int mrow=lane&15, koff=(lane>>4)*8;
  const int srow=tid>>2, scc=(tid&3)*8;

  f32x4v acc[2][2];
#pragma unroll
  for (int i=0;i<2;i++)
#pragma unroll
    for (int j=0;j<2;j++) acc[i][j] = (f32x4v){0.f,0.f,0.f,0.f};

  u16x8 sa0[2], sb0[2], sa1[2], sb1[2];
  auto load0 = [&](int it){
    const int pass = it>>3, kk=(it&7)<<6;
    const u16* Ap = (pass==2)?Al:Ah;
    const u16* Bp = (pass==1)?Bl:Bh;
    sa0[0] = *(const u16x8*)&Ap[(size_t)(bm+srow)*lda + kk + scc];
    sa0[1] = *(const u16x8*)&Ap[(size_t)(bm+srow)*lda + kk + scc + 32];
    sb0[0] = *(const u16x8*)&Bp[(size_t)(bn+srow)*ldb + kk + scc];
    sb0[1] = *(const u16x8*)&Bp[(size_t)(bn+srow)*ldb + kk + scc + 32];
  };
  auto load1 = [&](int it){
    const int pass = it>>3, kk=(it&7)<<6;
    const u16* Ap = (pass==2)?Al:Ah;
    const u16* Bp = (pass==1)?Bl:Bh;
    sa1[0] = *(const u16x8*)&Ap[(size_t)(bm+srow)*lda + kk + scc];
    sa1[1] = *(const u16x8*)&Ap[(size_t)(bm+srow)*lda + kk + scc + 32];
    sb1[0] = *(const u16x8*)&Bp[(size_t)(bn+srow)*ldb + kk + scc];
    sb1[1] = *(const u16x8*)&Bp[(size_t)(bn+srow)*ldb + kk + scc + 32];
  };

  load0(0);
  for (int it=0; it<24; it+=2){
    __syncthreads();
    *(u16x8*)&As[srow*STR+scc]    = sa0[0];
    *(u16x8*)&As[srow*STR+scc+32] = sa0[1];
    *(u16x8*)&Bs[srow*STR+scc]    = sb0[0];
    *(u16x8*)&Bs[srow*STR+scc+32] = sb0[1];
    if (it+1 < 24) load1(it+1);
    __syncthreads();
#pragma unroll
    for (int i=0;i<2;i++)
#pragma unroll
      for (int j=0;j<2;j++)
#pragma unroll
        for (int ks=0;ks<2;ks++){
          bf16x8v af = *(const bf16x8v*)&As[(wr*32+i*16+mrow)*STR + ks*32 + koff];
          bf16x8v bf = *(const bf16x8v*)&Bs[(wc*32+j*16+mrow)*STR + ks*32 + koff];
          acc[i][j] = __builtin_amdgcn_mfma_f32_16x16x32_bf16(af, bf, acc[i][j], 0,0,0);
        }
    if (it+1 >= 24) break;
    __syncthreads();
    *(u16x8*)&As[srow*STR+scc]    = sa1[0];
    *(u16x8*)&As[srow*STR+scc+32] = sa1[1];
    *(u16x8*)&Bs[srow*STR+scc]    = sb1[0];
    *(u16x8*)&Bs[srow*STR+scc+32] = sb1[1];
    if (it+2 < 24) load0(it+2);
    __syncthreads();
#pragma unroll
    for (int i=0;i<2;i++)
#pragma unroll
      for (int j=0;j<2;j++)
#pragma unroll
        for (int ks=0;ks<2;ks++){
          bf16x8v af = *(const bf16x8v*)&As[(wr*32+i*16+mrow)*STR + ks*32 + koff];
          bf16x8v bf = *(const bf16x8v*)&Bs[(wc*32+j*16+mrow)*STR + ks*32 + koff];
          acc[i][j] = __builtin_amdgcn_mfma_f32_16x16x32_bf16(af, bf, acc[i][j], 0,0,0);
        }
  }

  const int r0 = (lane>>4)*4, cn = lane&15;
  if constexpr (MODE==2){
#pragma unroll
    for (int i=0;i<2;i++)
#pragma unroll
      for (int j=0;j<2;j++)
#pragma unroll
        for (int r=0;r<4;r++){
          int m = bm + wr*32 + i*16 + r0 + r;       // m = s*512 + b
          int n2 = bn + wc*32 + j*16 + cn;
          if (n2 < MID_){
            int s = m >> 9, b = m & 511;
            Cout[((size_t)b*S_ + s)*MID_ + n2] = acc[i][j][r] + bias2[n2];
          }
        }
  } else {
#pragma unroll
    for (int i=0;i<2;i++)
#pragma unroll
      for (int j=0;j<2;j++)
#pragma unroll
        for (int r=0;r<4;r++){
          int row = bm + wr*32 + i*16 + r0 + r;
          int col = bn + wc*32 + j*16 + cn;
          float v = acc[i][j][r];
          if (bias2) v += bias2[col];
          Cout[(size_t)row*ldc + col] = v;
        }
  }
}

// ---------------------------------------------------------------------------
// Fused attention, 1024 threads (16 waves):
//   pp from combo[b][0:512] (fp32, ld 2560)
//   e[t] = sum_h Ws[h]*fast_tanh(projh[b,t,h]+pp[h]);
//   softmax WITHOUT max-subtraction (|e| <= sum|Ws| <= ~23, exp fp32-safe),
//   single-wave (wave 0, shfl_xor);
//   ctx[b,d] = sum_t alpha[t]*bHh[b,t,d], 2-deep row pipeline.
// ---------------------------------------------------------------------------
__global__ __launch_bounds__(1024) void attn_kernel(
    const u16* __restrict__ projh, const float* __restrict__ combo,
    const float* __restrict__ Wscore, const u16* __restrict__ bHh,
    u16* __restrict__ ctx_hi, u16* __restrict__ ctx_lo)
{
  __shared__ float s_e[T_];
  __shared__ float s_part[16][D_];
  const int tid=threadIdx.x, b=blockIdx.x, wave=tid>>6, lane=tid&63;

  float pv[8], wv[8];
  {
    const float* pprow = combo + (size_t)b*2560;
    float4 p0=*(const float4*)&pprow[lane*8], p1=*(const float4*)&pprow[lane*8+4];
    float4 w0=*(const float4*)&Wscore[lane*8], w1=*(const float4*)&Wscore[lane*8+4];
    pv[0]=p0.x;pv[1]=p0.y;pv[2]=p0.z;pv[3]=p0.w;pv[4]=p1.x;pv[5]=p1.y;pv[6]=p1.z;pv[7]=p1.w;
    wv[0]=w0.x;wv[1]=w0.y;wv[2]=w0.z;wv[3]=w0.w;wv[4]=w1.x;wv[5]=w1.y;wv[6]=w1.z;wv[7]=w1.w;
  }
  // e-phase: wave w handles t = w, w+16, ... (8 rows); 2-deep pipeline
  {
    const u16* base = projh + (size_t)b*T_*H_ + lane*8;
    u16x8 cur = *(const u16x8*)(base + (size_t)wave*H_);
    for (int t=wave; t<T_; t+=16){
      u16x8 nxt;
      if (t+16 < T_) nxt = *(const u16x8*)(base + (size_t)(t+16)*H_);
      float acc = 0.f;
#pragma unroll
      for (int j=0;j<8;j++) acc += wv[j]*fast_tanh(h2f_u(cur[j]) + pv[j]);
#pragma unroll
      for (int o=32;o>0;o>>=1) acc += __shfl_down(acc,o);
      if (lane==0) s_e[t] = acc;
      cur = nxt;
    }
  }
  __syncthreads();
  // single-wave softmax, no max subtraction (e bounded, exp safe in fp32)
  if (wave==0){
    float p0 = __expf(s_e[lane]), p1 = __expf(s_e[lane+64]);
    float ss = p0 + p1;
#pragma unroll
    for (int o=32;o>0;o>>=1) ss += __shfl_xor(ss,o);
    const float inv = __builtin_amdgcn_rcpf(ss);
    s_e[lane]    = p0*inv;
    s_e[lane+64] = p1*inv;
  }
  __syncthreads();

  // context: wave w covers t in [8w, 8w+8); lane covers d = lane*8..+7
  const int d0 = lane*8;
  float a[8] = {0,0,0,0,0,0,0,0};
  {
    const u16* base = bHh + (size_t)b*T_*D_ + d0;
    const int t0 = wave*8;
    u16x8 c0 = *(const u16x8*)(base + (size_t)t0*D_);
    u16x8 c1 = *(const u16x8*)(base + (size_t)(t0+1)*D_);
#pragma unroll
    for (int r=0;r<8;r++){
      u16x8 nxt;
      if (r+2 < 8) nxt = *(const u16x8*)(base + (size_t)(t0+r+2)*D_);
      const float al = s_e[t0+r];
#pragma unroll
      for (int j=0;j<8;j++) a[j] += al*h2f_u(c0[j]);
      c0 = c1; c1 = nxt;
    }
  }
  *(float4*)&s_part[wave][d0]   = make_float4(a[0],a[1],a[2],a[3]);
  *(float4*)&s_part[wave][d0+4] = make_float4(a[4],a[5],a[6],a[7]);
  __syncthreads();
  if (tid < D_){
    float vv = s_part[0][tid];
#pragma unroll
    for (int q=1;q<16;q++) vv += s_part[q][tid];
    u16 hh=f2bf_rn(vv), ll=f2bf_rn(vv-bf2f(hh));
    ctx_hi[(size_t)b*512 + tid] = hh;
    ctx_lo[(size_t)b*512 + tid] = ll;
  }
}

// ---------------------------------------------------------------------------
// Fused gates GEMM + LSTM pointwise (unchanged, proven).  K=512 bf16x2
// 3-pass, BK=64.  gates = ctx @ W_ih[:,:512]^T + combo[:,512:].
// ---------------------------------------------------------------------------
__global__ __launch_bounds__(256) void gates_lstm(
    const u16* __restrict__ Ah, const u16* __restrict__ Al,     // [512][512]
    const u16* __restrict__ Bh, const u16* __restrict__ Bl,     // [2048][512]
    const float* __restrict__ combo,                            // [512][2560]
    const float* __restrict__ WmT, const float* __restrict__ WbT,
    const int* __restrict__ midtok, const int* __restrict__ bottok,
    float* __restrict__ c,
    u16* __restrict__ hA_hi, u16* __restrict__ hA_lo,
    u16* __restrict__ hid_hi, u16* __restrict__ hid_lo, int s)
{
  constexpr int STR = 72;
  __shared__ short Bs[64*STR];
  const int tid=threadIdx.x, lane=tid&63, w=tid>>6;
  const int j0 = blockIdx.x*16, bm = blockIdx.y*64;
  const int mrow=lane&15, koff=(lane>>4)*8;
  const int arow = bm + w*16 + mrow;
  const int srow = tid>>2, scc=(tid&3)*8;
  const int sbrow = (srow>>4)*512 + j0 + (srow&15);

  f32x4v acc[4];
#pragma unroll
  for (int f=0;f<4;f++) acc[f] = (f32x4v){0.f,0.f,0.f,0.f};

  u16x8 sb0, sb1;
  bf16x8v a0[2], a1[2];
  auto loadB = [&](int it){
    const int pass = it>>3, kk=(it&7)<<6;
    const u16* Bp = (pass==1)?Bl:Bh;
    sb0 = *(const u16x8*)&Bp[(size_t)sbrow*512 + kk + scc];
    sb1 = *(const u16x8*)&Bp[(size_t)sbrow*512 + kk + scc + 32];
  };
  auto loadA0 = [&](int it){
    const int pass = it>>3, kk=(it&7)<<6;
    const u16* Ap = (pass==2)?Al:Ah;
    a0[0] = *(const bf16x8v*)&Ap[(size_t)arow*512 + kk + koff];
    a0[1] = *(const bf16x8v*)&Ap[(size_t)arow*512 + kk + koff + 32];
  };
  auto loadA1 = [&](int it){
    const int pass = it>>3, kk=(it&7)<<6;
    const u16* Ap = (pass==2)?Al:Ah;
    a1[0] = *(const bf16x8v*)&Ap[(size_t)arow*512 + kk + koff];
    a1[1] = *(const bf16x8v*)&Ap[(size_t)arow*512 + kk + koff + 32];
  };

  loadB(0); loadA0(0);
  for (int it=0; it<24; it+=2){
    __syncthreads();
    *(u16x8*)&Bs[srow*STR+scc]    = sb0;
    *(u16x8*)&Bs[srow*STR+scc+32] = sb1;
    if (it+1 < 24){ loadB(it+1); loadA1(it+1); }
    __syncthreads();
#pragma unroll
    for (int f=0;f<4;f++){
      bf16x8v b0 = *(const bf16x8v*)&Bs[(f*16+mrow)*STR + koff];
      bf16x8v b1 = *(const bf16x8v*)&Bs[(f*16+mrow)*STR + koff + 32];
      acc[f] = __builtin_amdgcn_mfma_f32_16x16x32_bf16(a0[0], b0, acc[f], 0,0,0);
      acc[f] = __builtin_amdgcn_mfma_f32_16x16x32_bf16(a0[1], b1, acc[f], 0,0,0);
    }
    if (it+1 >= 24) break;
    __syncthreads();
    *(u16x8*)&Bs[srow*STR+scc]    = sb0;
    *(u16x8*)&Bs[srow*STR+scc+32] = sb1;
    if (it+2 < 24){ loadB(it+2); loadA0(it+2); }
    __syncthreads();
#pragma unroll
    for (int f=0;f<4;f++){
      bf16x8v b0 = *(const bf16x8v*)&Bs[(f*16+mrow)*STR + koff];
      bf16x8v b1 = *(const bf16x8v*)&Bs[(f*16+mrow)*STR + koff + 32];
      acc[f] = __builtin_amdgcn_mfma_f32_16x16x32_bf16(a1[0], b0, acc[f], 0,0,0);
      acc[f] = __builtin_amdgcn_mfma_f32_16x16x32_bf16(a1[1], b1, acc[f], 0,0,0);
    }
  }

  // epilogue: lane holds gates f=0..3 for rows r0..r0+3 (b), col jj
  const int r0=(lane>>4)*4, jj=lane&15, j=j0+jj;
#pragma unroll
  for (int r=0;r<4;r++){
    const int b = bm + w*16 + r0 + r;
    const int mt = midtok[b*26 + s];
    const int bt = bottok[b*26 + s];
    const float* wm = WmT + (size_t)mt*2048;
    const float* wb = WbT + (size_t)bt*2048;
    const float* cb = combo + (size_t)b*2560 + 512;
    float ig = acc[0][r] + cb[j       ] + wm[j       ] + wb[j       ];
    float fg = acc[1][r] + cb[512 + j ] + wm[512 + j ] + wb[512 + j ];
    float gg = acc[2][r] + cb[1024 + j] + wm[1024 + j] + wb[1024 + j];
    float og = acc[3][r] + cb[1536 + j] + wm[1536 + j] + wb[1536 + j];
    ig = fast_sig(ig);
    fg = fast_sig(fg);
    gg = fast_tanh(gg);
    og = fast_sig(og);
    const size_t ci = (size_t)b*512 + j;
    const float cn = fg*c[ci] + ig*gg;
    const float hn = og*fast_tanh(cn);
    c[ci] = cn;
    u16 hh = f2bf_rn(hn), hl = f2bf_rn(hn - bf2f(hh));
    hA_hi[ci] = hh;
    hA_lo[ci] = hl;
    hid_hi[((size_t)s*512 + b)*512 + j] = hh;
    hid_lo[((size_t)s*512 + b)*512 + j] = hl;
  }
}

extern "C" void kernel_launch(void* const* d_in, const int* in_sizes, int n_in,
                              void* d_out, int out_size, void* d_ws, size_t ws_size,
                              hipStream_t stream) {
  const float* bH   = (const float*)d_in[0];
  const int*   midt = (const int*)  d_in[1];
  const int*   bott = (const int*)  d_in[2];
  const float* Wi2h = (const float*)d_in[3];
  const float* Wh2h = (const float*)d_in[4];
  const float* bh2h = (const float*)d_in[5];
  const float* Wsc  = (const float*)d_in[6];
  const float* Wih  = (const float*)d_in[7];
  const float* Whh  = (const float*)d_in[8];
  const float* bih  = (const float*)d_in[9];
  const float* bhh  = (const float*)d_in[10];
  const float* Wgen = (const float*)d_in[11];
  const float* bgen = (const float*)d_in[12];
  float* out = (float*)d_out;

  char* wp = (char*)d_ws;
  u16* projh   = (u16*)wp; wp += (size_t)B_*T_*H_*2;      // 67.1 MB fp16
  u16* bHh     = (u16*)wp; wp += (size_t)B_*T_*D_*2;      // 67.1 MB fp16
  u16* Bh2_hi  = (u16*)wp; wp += (size_t)2560*512*2;      // [W_h2h|W_hh] planes
  u16* Bh2_lo  = (u16*)wp; wp += (size_t)2560*512*2;
  u16* Bih_hi  = (u16*)wp; wp += (size_t)2048*512*2;      // W_ih[:, :512] planes
  u16* Bih_lo  = (u16*)wp; wp += (size_t)2048*512*2;
  u16* Wi2h_h  = (u16*)wp; wp += (size_t)512*512*2;       // fp16
  u16* Wg_hi   = (u16*)wp; wp += (size_t)64*512*2;
  u16* Wg_lo   = (u16*)wp; wp += (size_t)64*512*2;
  u16* ctx_hi  = (u16*)wp; wp += (size_t)B_*512*2;
  u16* ctx_lo  = (u16*)wp; wp += (size_t)B_*512*2;
  u16* hA_hi   = (u16*)wp; wp += (size_t)B_*512*2;
  u16* hA_lo   = (u16*)wp; wp += (size_t)B_*512*2;
  u16* hid_hi  = (u16*)wp; wp += (size_t)S_*B_*H_*2;      // 13.6 MB
  u16* hid_lo  = (u16*)wp; wp += (size_t)S_*B_*H_*2;
  float* combo = (float*)wp; wp += (size_t)B_*2560*4;     // 5.2 MB
  float* c     = (float*)wp; wp += (size_t)B_*H_*4;
  float* bcombF= (float*)wp; wp += (size_t)2560*4;
  float* WmT   = (float*)wp; wp += (size_t)MID_*2048*4;
  float* WbT   = (float*)wp; wp += (size_t)BOT_*2048*4;
  if ((size_t)(wp - (char*)d_ws) > ws_size) return;  // fail loudly

  setup_all<<<4096, 256, 0, stream>>>(
      bH, Wi2h, Wh2h, Whh, Wih, Wgen, bh2h, bih, bhh,
      bHh, Wi2h_h, Bh2_hi, Bh2_lo, Bih_hi, Bih_lo, Wg_hi, Wg_lo,
      WmT, WbT, bcombF, hA_hi, hA_lo, c);

  // proj = fp16( bHh @ Wi2h^T ), pure fp16, XCD-aware 1D grid
  gemm_proj16<<<2048, 256, 32768, stream>>>(bHh, Wi2h_h, projh);

  for (int s=0; s<S_; ++s){
    // combo = h @ [W_h2h | W_hh]^T + [b_h2h | b_ih+b_hh]  (bf16x2, BK=64)
    gemm_bf64<0><<<dim3(40,8), 256, 0, stream>>>(
        hA_hi, hA_lo, 512, Bh2_hi, Bh2_lo, 512,
        combo, 2560, bcombF);
    attn_kernel<<<B_, 1024, 0, stream>>>(
        projh, combo, Wsc, bHh, ctx_hi, ctx_lo);
    gates_lstm<<<dim3(32,8), 256, 0, stream>>>(
        ctx_hi, ctx_lo, Bih_hi, Bih_lo, combo, WmT, WbT,
        midt, bott, c, hA_hi, hA_lo,
        hid_hi, hid_lo, s);
  }

  // out = hid @ W_gen^T + b_gen  (bf16x2, BK=64), M = S*B = 13312
  gemm_bf64<2><<<dim3(1,208), 256, 0, stream>>>(
      hid_hi, hid_lo, 512, Wg_hi, Wg_lo, 512,
      out, 0, bgen);
}

// Round 15
// 1452.456 us; speedup vs baseline: 1.2511x; 1.0631x over previous
//
#include <hip/hip_runtime.h>
#include <hip/hip_bf16.h>
#include <hip/hip_fp16.h>
#include <cstdint>
#include <cstddef>

#define B_   512
#define T_   128
#define D_   512
#define H_   512
#define MID_ 38
#define BOT_ 38
#define S_   26
#define XL_  588   // D + MID + BOT = W_ih row length

typedef unsigned short u16;
typedef __attribute__((ext_vector_type(8))) short bf16x8v;
typedef __attribute__((ext_vector_type(8))) _Float16 f16x8v;
typedef __attribute__((ext_vector_type(8))) unsigned short u16x8;
typedef __attribute__((ext_vector_type(4))) float f32x4v;

__device__ __forceinline__ u16 f2bf_rn(float f){
  unsigned u = __float_as_uint(f);
  return (u16)((u + 0x7fffu + ((u>>16)&1u)) >> 16);
}
__device__ __forceinline__ float bf2f(u16 v){ return __uint_as_float(((unsigned)v)<<16); }
__device__ __forceinline__ u16 f2h_u(float f){ return __half_as_ushort(__float2half(f)); }
__device__ __forceinline__ float h2f_u(u16 u){ return __half2float(__ushort_as_half(u)); }

// branch-free fast transcendentals (v_exp_f32 + v_rcp_f32, ~1e-6 rel err)
__device__ __forceinline__ float fast_tanh(float x){
  return 1.0f - 2.0f*__builtin_amdgcn_rcpf(__expf(2.0f*x) + 1.0f);
}
__device__ __forceinline__ float fast_sig(float x){
  return __builtin_amdgcn_rcpf(1.0f + __expf(-x));
}

// ---------------------------------------------------------------------------
// One-shot setup: bH->fp16, weight conversions, token tables, bias combine,
// h/c zero-init.  Flat quad-index space, grid-stride.
// ---------------------------------------------------------------------------
__device__ __forceinline__ void cvt_hilo4(const float* src, u16* hi, u16* lo){
  float4 v = *(const float4*)src;
  ushort4 h, l;
  h.x=f2bf_rn(v.x); h.y=f2bf_rn(v.y); h.z=f2bf_rn(v.z); h.w=f2bf_rn(v.w);
  l.x=f2bf_rn(v.x-bf2f(h.x)); l.y=f2bf_rn(v.y-bf2f(h.y));
  l.z=f2bf_rn(v.z-bf2f(h.z)); l.w=f2bf_rn(v.w-bf2f(h.w));
  *(ushort4*)hi = h; *(ushort4*)lo = l;
}

__global__ __launch_bounds__(256) void setup_all(
    const float* __restrict__ bH,
    const float* __restrict__ Wi2h, const float* __restrict__ Wh2h,
    const float* __restrict__ Whh,  const float* __restrict__ Wih,
    const float* __restrict__ Wgen, const float* __restrict__ bh2h,
    const float* __restrict__ bih,  const float* __restrict__ bhh,
    u16* __restrict__ bHh,
    u16* __restrict__ Wi2h_h, u16* __restrict__ Bh2_hi, u16* __restrict__ Bh2_lo,
    u16* __restrict__ Bih_hi, u16* __restrict__ Bih_lo,
    u16* __restrict__ Wg_hi,  u16* __restrict__ Wg_lo,
    float* __restrict__ WmT, float* __restrict__ WbT, float* __restrict__ bcombF,
    u16* __restrict__ hA_hi, u16* __restrict__ hA_lo, float* __restrict__ c)
{
  const int T0 = 8388608;               // bH -> fp16 (65536 rows x 128 quads)
  const int T1 = T0+65536;              // Wi2h -> fp16
  const int T2 = T1+65536;              // Wh2h -> Bh2[0:512] hi/lo
  const int T3 = T2+262144;             // Whh  -> Bh2[512:2560]
  const int T4 = T3+262144;             // Wih[:, :512] -> Bih
  const int T5 = T4+8192;               // Wgen -> Wg (pad 64 rows)
  const int T6 = T5+19456;              // token tables (38*512 quads)
  const int T7 = T6+640;                // bcombF
  const int T8 = T7+65536;              // hA hi/lo zero (ushort4 each)
  const int T9 = T8+65536;              // c zero (float4)
  for (int i = blockIdx.x*256 + threadIdx.x; i < T9; i += gridDim.x*256){
    if (i < T0){
      int row=i>>7, c4=(i&127)*4;
      float4 v = *(const float4*)&bH[(size_t)row*512 + c4];
      ushort4 h; h.x=f2h_u(v.x); h.y=f2h_u(v.y); h.z=f2h_u(v.z); h.w=f2h_u(v.w);
      *(ushort4*)&bHh[(size_t)row*512 + c4] = h;
    } else if (i < T1){
      int j=i-T0, row=j>>7, c4=(j&127)*4;
      float4 v = *(const float4*)&Wi2h[(size_t)row*512 + c4];
      ushort4 h; h.x=f2h_u(v.x); h.y=f2h_u(v.y); h.z=f2h_u(v.z); h.w=f2h_u(v.w);
      *(ushort4*)&Wi2h_h[(size_t)row*512 + c4] = h;
    } else if (i < T2){
      int j=i-T1, row=j>>7, c4=(j&127)*4;
      cvt_hilo4(&Wh2h[(size_t)row*512+c4], &Bh2_hi[(size_t)row*512+c4], &Bh2_lo[(size_t)row*512+c4]);
    } else if (i < T3){
      int j=i-T2, row=j>>7, c4=(j&127)*4;
      cvt_hilo4(&Whh[(size_t)row*512+c4],
                &Bh2_hi[(size_t)(512+row)*512+c4], &Bh2_lo[(size_t)(512+row)*512+c4]);
    } else if (i < T4){
      int j=i-T3, row=j>>7, c4=(j&127)*4;
      cvt_hilo4(&Wih[(size_t)row*XL_+c4], &Bih_hi[(size_t)row*512+c4], &Bih_lo[(size_t)row*512+c4]);
    } else if (i < T5){
      int j=i-T4, row=j>>7, c4=(j&127)*4;
      float4 v = make_float4(0.f,0.f,0.f,0.f);
      if (row < MID_) v = *(const float4*)&Wgen[(size_t)row*512 + c4];
      ushort4 h, l;
      h.x=f2bf_rn(v.x); h.y=f2bf_rn(v.y); h.z=f2bf_rn(v.z); h.w=f2bf_rn(v.w);
      l.x=f2bf_rn(v.x-bf2f(h.x)); l.y=f2bf_rn(v.y-bf2f(h.y));
      l.z=f2bf_rn(v.z-bf2f(h.z)); l.w=f2bf_rn(v.w-bf2f(h.w));
      *(ushort4*)&Wg_hi[(size_t)row*512+c4] = h;
      *(ushort4*)&Wg_lo[(size_t)row*512+c4] = l;
    } else if (i < T6){
      int j=i-T5;                    // 38*512
      int cc=j>>9, jq=j&511;
#pragma unroll
      for (int u=0;u<4;u++){
        int jj=jq*4+u;
        WmT[(size_t)cc*2048+jj] = Wih[(size_t)jj*XL_ + 512 + cc];
        WbT[(size_t)cc*2048+jj] = Wih[(size_t)jj*XL_ + 512 + MID_ + cc];
      }
    } else if (i < T7){
      int j=(i-T6)*4;
#pragma unroll
      for (int u=0;u<4;u++){
        int k=j+u;
        if (k < 512) bcombF[k] = bh2h[k];
        else if (k < 2560) bcombF[k] = bih[k-512] + bhh[k-512];
      }
    } else if (i < T8){
      int j=i-T7;
      ushort4 z = {0,0,0,0};
      *(ushort4*)&hA_hi[(size_t)j*4] = z;
      *(ushort4*)&hA_lo[(size_t)j*4] = z;
    } else {
      int j=i-T8;
      *(float4*)&c[(size_t)j*4] = make_float4(0.f,0.f,0.f,0.f);
    }
  }
}

// ---------------------------------------------------------------------------
// proj GEMM, pure fp16, BM=BN=128, XCD-aware 1D grid (2048 blocks),
// reg-staged with 1-ahead prefetch (R11-proven).
// A = bHh fp16, B = Wi2h fp16.  C = fp16 projh via LDS bounce.
// ---------------------------------------------------------------------------
__global__ __launch_bounds__(256) void gemm_proj16(
    const u16* __restrict__ Ah, const u16* __restrict__ Bh,
    u16* __restrict__ projh)
{
  extern __shared__ char smem[];
  constexpr int STR = 40;
  short* As = (short*)smem;                  // [128][STR]
  short* Bs = As + 128*STR;
  const int tid=threadIdx.x;
  const int n = blockIdx.x;
  const int x = n & 7, q = n >> 3;
  const int bn = (q & 3) * 128;
  const int bm = ((q >> 2)*8 + x) * 128;
  const int w=tid>>6, lane=tid&63, wr=w>>1, wc=w&1;

  f32x4v acc[4][4];
#pragma unroll
  for (int i=0;i<4;i++)
#pragma unroll
    for (int j=0;j<4;j++) acc[i][j] = (f32x4v){0.f,0.f,0.f,0.f};

  u16x8 ra[2], rb[2];
  auto load = [&](int it){
    const int kk = it<<5;
#pragma unroll
    for (int L=0; L<2; L++){
      int t=L*256+tid, row=t>>2, c=(t&3)*8;
      ra[L] = *(const u16x8*)&Ah[(size_t)(bm+row)*512 + kk + c];
      rb[L] = *(const u16x8*)&Bh[(size_t)(bn+row)*512 + kk + c];
    }
  };
  load(0);

  for (int it=0; it<16; ++it){
    __syncthreads();
#pragma unroll
    for (int L=0; L<2; L++){
      int t=L*256+tid, row=t>>2, c=(t&3)*8;
      *(u16x8*)&As[row*STR+c] = ra[L];
      *(u16x8*)&Bs[row*STR+c] = rb[L];
    }
    if (it+1 < 16) load(it+1);
    __syncthreads();
    const int koff = (lane>>4)*8, mrow = lane&15;
#pragma unroll
    for (int i=0;i<4;i++)
#pragma unroll
      for (int j=0;j<4;j++){
        f16x8v af = *(const f16x8v*)&As[(wr*64+i*16+mrow)*STR + koff];
        f16x8v bf = *(const f16x8v*)&Bs[(wc*64+j*16+mrow)*STR + koff];
        acc[i][j] = __builtin_amdgcn_mfma_f32_16x16x32_f16(af, bf, acc[i][j], 0,0,0);
      }
  }

  // epilogue: fp16 out via LDS bounce
  const int r0 = (lane>>4)*4, cn = lane&15;
  __syncthreads();
  u16* Ts = (u16*)smem;   // [128][128]
#pragma unroll
  for (int i=0;i<4;i++)
#pragma unroll
    for (int j=0;j<4;j++)
#pragma unroll
      for (int r=0;r<4;r++)
        Ts[(wr*64+i*16+r0+r)*128 + wc*64+j*16+cn] = f2h_u(acc[i][j][r]);
  __syncthreads();
#pragma unroll
  for (int q2=0;q2<8;q2++){
    int idx = q2*256 + tid;
    int row = idx>>4, c8 = (idx&15)*8;
    *(float4*)&projh[(size_t)(bm+row)*512 + bn + c8] = *(const float4*)&Ts[row*128 + c8];
  }
}

// ---------------------------------------------------------------------------
// bf16 MFMA GEMM 64x64, K=512, bf16x2 3-pass, BK=64, STR=72 pad,
// register ping-pong with 1-ahead prefetch.
// MODE 0: fp32 out + col-bias.  MODE 2: generator out (m->(s,b), n<38, +bias2).
// ---------------------------------------------------------------------------
template<int MODE>
__global__ __launch_bounds__(256) void gemm_bf64(
    const u16* __restrict__ Ah, const u16* __restrict__ Al, int lda,
    const u16* __restrict__ Bh, const u16* __restrict__ Bl, int ldb,
    float* __restrict__ Cout, int ldc, const float* __restrict__ bias2)
{
  constexpr int STR = 72;                  // 64 + 8 pad (2-way read, free)
  __shared__ short As[64*STR];
  __shared__ short Bs[64*STR];
  const int tid=threadIdx.x, lane=tid&63, w=tid>>6, wr=w>>1, wc=w&1;
  const int bm=blockIdx.y*64, bn=blockIdx.x*64;
  const int mrow=lane&15, koff=(lane>>4)*8;
  const int srow=tid>>2, scc=(tid&3)*8;

  f32x4v acc[2][2];
#pragma unroll
  for (int i=0;i<2;i++)
#pragma unroll
    for (int j=0;j<2;j++) acc[i][j] = (f32x4v){0.f,0.f,0.f,0.f};

  u16x8 sa0[2], sb0[2], sa1[2], sb1[2];
  auto load0 = [&](int it){
    const int pass = it>>3, kk=(it&7)<<6;
    const u16* Ap = (pass==2)?Al:Ah;
    const u16* Bp = (pass==1)?Bl:Bh;
    sa0[0] = *(const u16x8*)&Ap[(size_t)(bm+srow)*lda + kk + scc];
    sa0[1] = *(const u16x8*)&Ap[(size_t)(bm+srow)*lda + kk + scc + 32];
    sb0[0] = *(const u16x8*)&Bp[(size_t)(bn+srow)*ldb + kk + scc];
    sb0[1] = *(const u16x8*)&Bp[(size_t)(bn+srow)*ldb + kk + scc + 32];
  };
  auto load1 = [&](int it){
    const int pass = it>>3, kk=(it&7)<<6;
    const u16* Ap = (pass==2)?Al:Ah;
    const u16* Bp = (pass==1)?Bl:Bh;
    sa1[0] = *(const u16x8*)&Ap[(size_t)(bm+srow)*lda + kk + scc];
    sa1[1] = *(const u16x8*)&Ap[(size_t)(bm+srow)*lda + kk + scc + 32];
    sb1[0] = *(const u16x8*)&Bp[(size_t)(bn+srow)*ldb + kk + scc];
    sb1[1] = *(const u16x8*)&Bp[(size_t)(bn+srow)*ldb + kk + scc + 32];
  };

  load0(0);
  for (int it=0; it<24; it+=2){
    __syncthreads();
    *(u16x8*)&As[srow*STR+scc]    = sa0[0];
    *(u16x8*)&As[srow*STR+scc+32] = sa0[1];
    *(u16x8*)&Bs[srow*STR+scc]    = sb0[0];
    *(u16x8*)&Bs[srow*STR+scc+32] = sb0[1];
    if (it+1 < 24) load1(it+1);
    __syncthreads();
#pragma unroll
    for (int i=0;i<2;i++)
#pragma unroll
      for (int j=0;j<2;j++)
#pragma unroll
        for (int ks=0;ks<2;ks++){
          bf16x8v af = *(const bf16x8v*)&As[(wr*32+i*16+mrow)*STR + ks*32 + koff];
          bf16x8v bf = *(const bf16x8v*)&Bs[(wc*32+j*16+mrow)*STR + ks*32 + koff];
          acc[i][j] = __builtin_amdgcn_mfma_f32_16x16x32_bf16(af, bf, acc[i][j], 0,0,0);
        }
    if (it+1 >= 24) break;
    __syncthreads();
    *(u16x8*)&As[srow*STR+scc]    = sa1[0];
    *(u16x8*)&As[srow*STR+scc+32] = sa1[1];
    *(u16x8*)&Bs[srow*STR+scc]    = sb1[0];
    *(u16x8*)&Bs[srow*STR+scc+32] = sb1[1];
    if (it+2 < 24) load0(it+2);
    __syncthreads();
#pragma unroll
    for (int i=0;i<2;i++)
#pragma unroll
      for (int j=0;j<2;j++)
#pragma unroll
        for (int ks=0;ks<2;ks++){
          bf16x8v af = *(const bf16x8v*)&As[(wr*32+i*16+mrow)*STR + ks*32 + koff];
          bf16x8v bf = *(const bf16x8v*)&Bs[(wc*32+j*16+mrow)*STR + ks*32 + koff];
          acc[i][j] = __builtin_amdgcn_mfma_f32_16x16x32_bf16(af, bf, acc[i][j], 0,0,0);
        }
  }

  const int r0 = (lane>>4)*4, cn = lane&15;
  if constexpr (MODE==2){
#pragma unroll
    for (int i=0;i<2;i++)
#pragma unroll
      for (int j=0;j<2;j++)
#pragma unroll
        for (int r=0;r<4;r++){
          int m = bm + wr*32 + i*16 + r0 + r;       // m = s*512 + b
          int n2 = bn + wc*32 + j*16 + cn;
          if (n2 < MID_){
            int s = m >> 9, b = m & 511;
            Cout[((size_t)b*S_ + s)*MID_ + n2] = acc[i][j][r] + bias2[n2];
          }
        }
  } else {
#pragma unroll
    for (int i=0;i<2;i++)
#pragma unroll
      for (int j=0;j<2;j++)
#pragma unroll
        for (int r=0;r<4;r++){
          int row = bm + wr*32 + i*16 + r0 + r;
          int col = bn + wc*32 + j*16 + cn;
          float v = acc[i][j][r];
          if (bias2) v += bias2[col];
          Cout[(size_t)row*ldc + col] = v;
        }
  }
}

// ---------------------------------------------------------------------------
// Fused attention, 1024 threads (16 waves):
//   pp from combo[b][0:512] (fp32, ld 2560)
//   e[t] = sum_h Ws[h]*fast_tanh(projh[b,t,h]+pp[h]);
//   no-max single-wave softmax (|e| <= sum|Ws| ~ 23, exp fp32-safe);
//   ctx[b,d] = sum_t alpha[t]*bHh[b,t,d].
// Both phases use 4-row register load-batches (up to 8 loads in flight/lane).
// ---------------------------------------------------------------------------
__global__ __launch_bounds__(1024) void attn_kernel(
    const u16* __restrict__ projh, const float* __restrict__ combo,
    const float* __restrict__ Wscore, const u16* __restrict__ bHh,
    u16* __restrict__ ctx_hi, u16* __restrict__ ctx_lo)
{
  __shared__ float s_e[T_];
  __shared__ float s_part[16][D_];
  const int tid=threadIdx.x, b=blockIdx.x, wave=tid>>6, lane=tid&63;

  float pv[8], wv[8];
  {
    const float* pprow = combo + (size_t)b*2560;
    float4 p0=*(const float4*)&pprow[lane*8], p1=*(const float4*)&pprow[lane*8+4];
    float4 w0=*(const float4*)&Wscore[lane*8], w1=*(const float4*)&Wscore[lane*8+4];
    pv[0]=p0.x;pv[1]=p0.y;pv[2]=p0.z;pv[3]=p0.w;pv[4]=p1.x;pv[5]=p1.y;pv[6]=p1.z;pv[7]=p1.w;
    wv[0]=w0.x;wv[1]=w0.y;wv[2]=w0.z;wv[3]=w0.w;wv[4]=w1.x;wv[5]=w1.y;wv[6]=w1.z;wv[7]=w1.w;
  }
  // e-phase: wave w owns t = w + 16k, k=0..7.  Two 4-row batches, loads of
  // both batches issued before compute of the first (8 loads in flight).
  {
    const u16* base = projh + (size_t)b*T_*H_ + lane*8;
    u16x8 rA[4], rB[4];
#pragma unroll
    for (int k=0;k<4;k++) rA[k] = *(const u16x8*)(base + (size_t)(wave+16*k)*H_);
#pragma unroll
    for (int k=0;k<4;k++) rB[k] = *(const u16x8*)(base + (size_t)(wave+16*(k+4))*H_);
#pragma unroll
    for (int k=0;k<4;k++){
      float acc = 0.f;
#pragma unroll
      for (int j=0;j<8;j++) acc += wv[j]*fast_tanh(h2f_u(rA[k][j]) + pv[j]);
#pragma unroll
      for (int o=32;o>0;o>>=1) acc += __shfl_down(acc,o);
      if (lane==0) s_e[wave+16*k] = acc;
    }
#pragma unroll
    for (int k=0;k<4;k++){
      float acc = 0.f;
#pragma unroll
      for (int j=0;j<8;j++) acc += wv[j]*fast_tanh(h2f_u(rB[k][j]) + pv[j]);
#pragma unroll
      for (int o=32;o>0;o>>=1) acc += __shfl_down(acc,o);
      if (lane==0) s_e[wave+16*(k+4)] = acc;
    }
  }
  __syncthreads();
  // single-wave softmax, no max subtraction (e bounded, exp safe in fp32)
  if (wave==0){
    float p0 = __expf(s_e[lane]), p1 = __expf(s_e[lane+64]);
    float ss = p0 + p1;
#pragma unroll
    for (int o=32;o>0;o>>=1) ss += __shfl_xor(ss,o);
    const float inv = __builtin_amdgcn_rcpf(ss);
    s_e[lane]    = p0*inv;
    s_e[lane+64] = p1*inv;
  }
  __syncthreads();

  // context: wave w covers t in [8w, 8w+8); all 8 rows loaded upfront
  const int d0 = lane*8;
  float a[8] = {0,0,0,0,0,0,0,0};
  {
    const u16* base = bHh + (size_t)b*T_*D_ + d0;
    const int t0 = wave*8;
    u16x8 rr[8];
#pragma unroll
    for (int r=0;r<8;r++) rr[r] = *(const u16x8*)(base + (size_t)(t0+r)*D_);
#pragma unroll
    for (int r=0;r<8;r++){
      const float al = s_e[t0+r];
#pragma unroll
      for (int j=0;j<8;j++) a[j] += al*h2f_u(rr[r][j]);
    }
  }
  *(float4*)&s_part[wave][d0]   = make_float4(a[0],a[1],a[2],a[3]);
  *(float4*)&s_part[wave][d0+4] = make_float4(a[4],a[5],a[6],a[7]);
  __syncthreads();
  if (tid < D_){
    float vv = s_part[0][tid];
#pragma unroll
    for (int q=1;q<16;q++) vv += s_part[q][tid];
    u16 hh=f2bf_rn(vv), ll=f2bf_rn(vv-bf2f(hh));
    ctx_hi[(size_t)b*512 + tid] = hh;
    ctx_lo[(size_t)b*512 + tid] = ll;
  }
}

// ---------------------------------------------------------------------------
// Fused gates GEMM + LSTM pointwise (unchanged, proven).  K=512 bf16x2
// 3-pass, BK=64.  gates = ctx @ W_ih[:,:512]^T + combo[:,512:].
// ---------------------------------------------------------------------------
__global__ __launch_bounds__(256) void gates_lstm(
    const u16* __restrict__ Ah, const u16* __restrict__ Al,     // [512][512]
    const u16* __restrict__ Bh, const u16* __restrict__ Bl,     // [2048][512]
    const float* __restrict__ combo,                            // [512][2560]
    const float* __restrict__ WmT, const float* __restrict__ WbT,
    const int* __restrict__ midtok, const int* __restrict__ bottok,
    float* __restrict__ c,
    u16* __restrict__ hA_hi, u16* __restrict__ hA_lo,
    u16* __restrict__ hid_hi, u16* __restrict__ hid_lo, int s)
{
  constexpr int STR = 72;
  __shared__ short Bs[64*STR];
  const int tid=threadIdx.x, lane=tid&63, w=tid>>6;
  const int j0 = blockIdx.x*16, bm = blockIdx.y*64;
  const int mrow=lane&15, koff=(lane>>4)*8;
  const int arow = bm + w*16 + mrow;
  const int srow = tid>>2, scc=(tid&3)*8;
  const int sbrow = (srow>>4)*512 + j0 + (srow&15);

  f32x4v acc[4];
#pragma unroll
  for (int f=0;f<4;f++) acc[f] = (f32x4v){0.f,0.f,0.f,0.f};

  u16x8 sb0, sb1;
  bf16x8v a0[2], a1[2];
  auto loadB = [&](int it){
    const int pass = it>>3, kk=(it&7)<<6;
    const u16* Bp = (pass==1)?Bl:Bh;
    sb0 = *(const u16x8*)&Bp[(size_t)sbrow*512 + kk + scc];
    sb1 = *(const u16x8*)&Bp[(size_t)sbrow*512 + kk + scc + 32];
  };
  auto loadA0 = [&](int it){
    const int pass = it>>3, kk=(it&7)<<6;
    const u16* Ap = (pass==2)?Al:Ah;
    a0[0] = *(const bf16x8v*)&Ap[(size_t)arow*512 + kk + koff];
    a0[1] = *(const bf16x8v*)&Ap[(size_t)arow*512 + kk + koff + 32];
  };
  auto loadA1 = [&](int it){
    const int pass = it>>3, kk=(it&7)<<6;
    const u16* Ap = (pass==2)?Al:Ah;
    a1[0] = *(const bf16x8v*)&Ap[(size_t)arow*512 + kk + koff];
    a1[1] = *(const bf16x8v*)&Ap[(size_t)arow*512 + kk + koff + 32];
  };

  loadB(0); loadA0(0);
  for (int it=0; it<24; it+=2){
    __syncthreads();
    *(u16x8*)&Bs[srow*STR+scc]    = sb0;
    *(u16x8*)&Bs[srow*STR+scc+32] = sb1;
    if (it+1 < 24){ loadB(it+1); loadA1(it+1); }
    __syncthreads();
#pragma unroll
    for (int f=0;f<4;f++){
      bf16x8v b0 = *(const bf16x8v*)&Bs[(f*16+mrow)*STR + koff];
      bf16x8v b1 = *(const bf16x8v*)&Bs[(f*16+mrow)*STR + koff + 32];
      acc[f] = __builtin_amdgcn_mfma_f32_16x16x32_bf16(a0[0], b0, acc[f], 0,0,0);
      acc[f] = __builtin_amdgcn_mfma_f32_16x16x32_bf16(a0[1], b1, acc[f], 0,0,0);
    }
    if (it+1 >= 24) break;
    __syncthreads();
    *(u16x8*)&Bs[srow*STR+scc]    = sb0;
    *(u16x8*)&Bs[srow*STR+scc+32] = sb1;
    if (it+2 < 24){ loadB(it+2); loadA0(it+2); }
    __syncthreads();
#pragma unroll
    for (int f=0;f<4;f++){
      bf16x8v b0 = *(const bf16x8v*)&Bs[(f*16+mrow)*STR + koff];
      bf16x8v b1 = *(const bf16x8v*)&Bs[(f*16+mrow)*STR + koff + 32];
      acc[f] = __builtin_amdgcn_mfma_f32_16x16x32_bf16(a1[0], b0, acc[f], 0,0,0);
      acc[f] = __builtin_amdgcn_mfma_f32_16x16x32_bf16(a1[1], b1, acc[f], 0,0,0);
    }
  }

  // epilogue: lane holds gates f=0..3 for rows r0..r0+3 (b), col jj
  const int r0=(lane>>4)*4, jj=lane&15, j=j0+jj;
#pragma unroll
  for (int r=0;r<4;r++){
    const int b = bm + w*16 + r0 + r;
    const int mt = midtok[b*26 + s];
    const int bt = bottok[b*26 + s];
    const float* wm = WmT + (size_t)mt*2048;
    const float* wb = WbT + (size_t)bt*2048;
    const float* cb = combo + (size_t)b*2560 + 512;
    float ig = acc[0][r] + cb[j       ] + wm[j       ] + wb[j       ];
    float fg = acc[1][r] + cb[512 + j ] + wm[512 + j ] + wb[512 + j ];
    float gg = acc[2][r] + cb[1024 + j] + wm[1024 + j] + wb[1024 + j];
    float og = acc[3][r] + cb[1536 + j] + wm[1536 + j] + wb[1536 + j];
    ig = fast_sig(ig);
    fg = fast_sig(fg);
    gg = fast_tanh(gg);
    og = fast_sig(og);
    const size_t ci = (size_t)b*512 + j;
    const float cn = fg*c[ci] + ig*gg;
    const float hn = og*fast_tanh(cn);
    c[ci] = cn;
    u16 hh = f2bf_rn(hn), hl = f2bf_rn(hn - bf2f(hh));
    hA_hi[ci] = hh;
    hA_lo[ci] = hl;
    hid_hi[((size_t)s*512 + b)*512 + j] = hh;
    hid_lo[((size_t)s*512 + b)*512 + j] = hl;
  }
}

extern "C" void kernel_launch(void* const* d_in, const int* in_sizes, int n_in,
                              void* d_out, int out_size, void* d_ws, size_t ws_size,
                              hipStream_t stream) {
  const float* bH   = (const float*)d_in[0];
  const int*   midt = (const int*)  d_in[1];
  const int*   bott = (const int*)  d_in[2];
  const float* Wi2h = (const float*)d_in[3];
  const float* Wh2h = (const float*)d_in[4];
  const float* bh2h = (const float*)d_in[5];
  const float* Wsc  = (const float*)d_in[6];
  const float* Wih  = (const float*)d_in[7];
  const float* Whh  = (const float*)d_in[8];
  const float* bih  = (const float*)d_in[9];
  const float* bhh  = (const float*)d_in[10];
  const float* Wgen = (const float*)d_in[11];
  const float* bgen = (const float*)d_in[12];
  float* out = (float*)d_out;

  char* wp = (char*)d_ws;
  u16* projh   = (u16*)wp; wp += (size_t)B_*T_*H_*2;      // 67.1 MB fp16
  u16* bHh     = (u16*)wp; wp += (size_t)B_*T_*D_*2;      // 67.1 MB fp16
  u16* Bh2_hi  = (u16*)wp; wp += (size_t)2560*512*2;      // [W_h2h|W_hh] planes
  u16* Bh2_lo  = (u16*)wp; wp += (size_t)2560*512*2;
  u16* Bih_hi  = (u16*)wp; wp += (size_t)2048*512*2;      // W_ih[:, :512] planes
  u16* Bih_lo  = (u16*)wp; wp += (size_t)2048*512*2;
  u16* Wi2h_h  = (u16*)wp; wp += (size_t)512*512*2;       // fp16
  u16* Wg_hi   = (u16*)wp; wp += (size_t)64*512*2;
  u16* Wg_lo   = (u16*)wp; wp += (size_t)64*512*2;
  u16* ctx_hi  = (u16*)wp; wp += (size_t)B_*512*2;
  u16* ctx_lo  = (u16*)wp; wp += (size_t)B_*512*2;
  u16* hA_hi   = (u16*)wp; wp += (size_t)B_*512*2;
  u16* hA_lo   = (u16*)wp; wp += (size_t)B_*512*2;
  u16* hid_hi  = (u16*)wp; wp += (size_t)S_*B_*H_*2;      // 13.6 MB
  u16* hid_lo  = (u16*)wp; wp += (size_t)S_*B_*H_*2;
  float* combo = (float*)wp; wp += (size_t)B_*2560*4;     // 5.2 MB
  float* c     = (float*)wp; wp += (size_t)B_*H_*4;
  float* bcombF= (float*)wp; wp += (size_t)2560*4;
  float* WmT   = (float*)wp; wp += (size_t)MID_*2048*4;
  float* WbT   = (float*)wp; wp += (size_t)BOT_*2048*4;
  if ((size_t)(wp - (char*)d_ws) > ws_size) return;  // fail loudly

  setup_all<<<4096, 256, 0, stream>>>(
      bH, Wi2h, Wh2h, Whh, Wih, Wgen, bh2h, bih, bhh,
      bHh, Wi2h_h, Bh2_hi, Bh2_lo, Bih_hi, Bih_lo, Wg_hi, Wg_lo,
      WmT, WbT, bcombF, hA_hi, hA_lo, c);

  // proj = fp16( bHh @ Wi2h^T ), pure fp16, XCD-aware 1D grid
  gemm_proj16<<<2048, 256, 32768, stream>>>(bHh, Wi2h_h, projh);

  for (int s=0; s<S_; ++s){
    // combo = h @ [W_h2h | W_hh]^T + [b_h2h | b_ih+b_hh]  (bf16x2, BK=64)
    gemm_bf64<0><<<dim3(40,8), 256, 0, stream>>>(
        hA_hi, hA_lo, 512, Bh2_hi, Bh2_lo, 512,
        combo, 2560, bcombF);
    attn_kernel<<<B_, 1024, 0, stream>>>(
        projh, combo, Wsc, bHh, ctx_hi, ctx_lo);
    gates_lstm<<<dim3(32,8), 256, 0, stream>>>(
        ctx_hi, ctx_lo, Bih_hi, Bih_lo, combo, WmT, WbT,
        midt, bott, c, hA_hi, hA_lo,
        hid_hi, hid_lo, s);
  }

  // out = hid @ W_gen^T + b_gen  (bf16x2, BK=64), M = S*B = 13312
  gemm_bf64<2><<<dim3(1,208), 256, 0, stream>>>(
      hid_hi, hid_lo, 512, Wg_hi, Wg_lo, 512,
      out, 0, bgen);
}

// Round 16
// 1332.661 us; speedup vs baseline: 1.3635x; 1.0899x over previous
//
#include <hip/hip_runtime.h>
#include <hip/hip_bf16.h>
#include <hip/hip_fp16.h>
#include <cstdint>
#include <cstddef>

#define B_   512
#define T_   128
#define D_   512
#define H_   512
#define MID_ 38
#define BOT_ 38
#define S_   26
#define XL_  588   // D + MID + BOT = W_ih row length

typedef unsigned short u16;
typedef __attribute__((ext_vector_type(8))) short bf16x8v;
typedef __attribute__((ext_vector_type(8))) _Float16 f16x8v;
typedef __attribute__((ext_vector_type(8))) unsigned short u16x8;
typedef __attribute__((ext_vector_type(4))) float f32x4v;

__device__ __forceinline__ u16 f2bf_rn(float f){
  unsigned u = __float_as_uint(f);
  return (u16)((u + 0x7fffu + ((u>>16)&1u)) >> 16);
}
__device__ __forceinline__ float bf2f(u16 v){ return __uint_as_float(((unsigned)v)<<16); }
__device__ __forceinline__ u16 f2h_u(float f){ return __half_as_ushort(__float2half(f)); }
__device__ __forceinline__ float h2f_u(u16 u){ return __half2float(__ushort_as_half(u)); }

// branch-free fast transcendentals (v_exp_f32 + v_rcp_f32, ~1e-6 rel err)
__device__ __forceinline__ float fast_tanh(float x){
  return 1.0f - 2.0f*__builtin_amdgcn_rcpf(__expf(2.0f*x) + 1.0f);
}
__device__ __forceinline__ float fast_sig(float x){
  return __builtin_amdgcn_rcpf(1.0f + __expf(-x));
}

// ---------------------------------------------------------------------------
// One-shot setup: bH->fp16, weight conversions, token tables, bias combine,
// h/c zero-init.  Flat quad-index space, grid-stride.
// ---------------------------------------------------------------------------
__device__ __forceinline__ void cvt_hilo4(const float* src, u16* hi, u16* lo){
  float4 v = *(const float4*)src;
  ushort4 h, l;
  h.x=f2bf_rn(v.x); h.y=f2bf_rn(v.y); h.z=f2bf_rn(v.z); h.w=f2bf_rn(v.w);
  l.x=f2bf_rn(v.x-bf2f(h.x)); l.y=f2bf_rn(v.y-bf2f(h.y));
  l.z=f2bf_rn(v.z-bf2f(h.z)); l.w=f2bf_rn(v.w-bf2f(h.w));
  *(ushort4*)hi = h; *(ushort4*)lo = l;
}

__global__ __launch_bounds__(256) void setup_all(
    const float* __restrict__ bH,
    const float* __restrict__ Wi2h, const float* __restrict__ Wh2h,
    const float* __restrict__ Whh,  const float* __restrict__ Wih,
    const float* __restrict__ Wgen, const float* __restrict__ bh2h,
    const float* __restrict__ bih,  const float* __restrict__ bhh,
    u16* __restrict__ bHh,
    u16* __restrict__ Wi2h_h, u16* __restrict__ Bh2_hi, u16* __restrict__ Bh2_lo,
    u16* __restrict__ Bih_hi, u16* __restrict__ Bih_lo,
    u16* __restrict__ Wg_hi,  u16* __restrict__ Wg_lo,
    float* __restrict__ WmT, float* __restrict__ WbT, float* __restrict__ bcombF,
    u16* __restrict__ hA_hi, u16* __restrict__ hA_lo, float* __restrict__ c)
{
  const int T0 = 8388608;               // bH -> fp16 (65536 rows x 128 quads)
  const int T1 = T0+65536;              // Wi2h -> fp16
  const int T2 = T1+65536;              // Wh2h -> Bh2[0:512] hi/lo
  const int T3 = T2+262144;             // Whh  -> Bh2[512:2560]
  const int T4 = T3+262144;             // Wih[:, :512] -> Bih
  const int T5 = T4+8192;               // Wgen -> Wg (pad 64 rows)
  const int T6 = T5+19456;              // token tables (38*512 quads)
  const int T7 = T6+640;                // bcombF
  const int T8 = T7+65536;              // hA hi/lo zero (ushort4 each)
  const int T9 = T8+65536;              // c zero (float4)
  for (int i = blockIdx.x*256 + threadIdx.x; i < T9; i += gridDim.x*256){
    if (i < T0){
      int row=i>>7, c4=(i&127)*4;
      float4 v = *(const float4*)&bH[(size_t)row*512 + c4];
      ushort4 h; h.x=f2h_u(v.x); h.y=f2h_u(v.y); h.z=f2h_u(v.z); h.w=f2h_u(v.w);
      *(ushort4*)&bHh[(size_t)row*512 + c4] = h;
    } else if (i < T1){
      int j=i-T0, row=j>>7, c4=(j&127)*4;
      float4 v = *(const float4*)&Wi2h[(size_t)row*512 + c4];
      ushort4 h; h.x=f2h_u(v.x); h.y=f2h_u(v.y); h.z=f2h_u(v.z); h.w=f2h_u(v.w);
      *(ushort4*)&Wi2h_h[(size_t)row*512 + c4] = h;
    } else if (i < T2){
      int j=i-T1, row=j>>7, c4=(j&127)*4;
      cvt_hilo4(&Wh2h[(size_t)row*512+c4], &Bh2_hi[(size_t)row*512+c4], &Bh2_lo[(size_t)row*512+c4]);
    } else if (i < T3){
      int j=i-T2, row=j>>7, c4=(j&127)*4;
      cvt_hilo4(&Whh[(size_t)row*512+c4],
                &Bh2_hi[(size_t)(512+row)*512+c4], &Bh2_lo[(size_t)(512+row)*512+c4]);
    } else if (i < T4){
      int j=i-T3, row=j>>7, c4=(j&127)*4;
      cvt_hilo4(&Wih[(size_t)row*XL_+c4], &Bih_hi[(size_t)row*512+c4], &Bih_lo[(size_t)row*512+c4]);
    } else if (i < T5){
      int j=i-T4, row=j>>7, c4=(j&127)*4;
      float4 v = make_float4(0.f,0.f,0.f,0.f);
      if (row < MID_) v = *(const float4*)&Wgen[(size_t)row*512 + c4];
      ushort4 h, l;
      h.x=f2bf_rn(v.x); h.y=f2bf_rn(v.y); h.z=f2bf_rn(v.z); h.w=f2bf_rn(v.w);
      l.x=f2bf_rn(v.x-bf2f(h.x)); l.y=f2bf_rn(v.y-bf2f(h.y));
      l.z=f2bf_rn(v.z-bf2f(h.z)); l.w=f2bf_rn(v.w-bf2f(h.w));
      *(ushort4*)&Wg_hi[(size_t)row*512+c4] = h;
      *(ushort4*)&Wg_lo[(size_t)row*512+c4] = l;
    } else if (i < T6){
      int j=i-T5;                    // 38*512
      int cc=j>>9, jq=j&511;
#pragma unroll
      for (int u=0;u<4;u++){
        int jj=jq*4+u;
        WmT[(size_t)cc*2048+jj] = Wih[(size_t)jj*XL_ + 512 + cc];
        WbT[(size_t)cc*2048+jj] = Wih[(size_t)jj*XL_ + 512 + MID_ + cc];
      }
    } else if (i < T7){
      int j=(i-T6)*4;
#pragma unroll
      for (int u=0;u<4;u++){
        int k=j+u;
        if (k < 512) bcombF[k] = bh2h[k];
        else if (k < 2560) bcombF[k] = bih[k-512] + bhh[k-512];
      }
    } else if (i < T8){
      int j=i-T7;
      ushort4 z = {0,0,0,0};
      *(ushort4*)&hA_hi[(size_t)j*4] = z;
      *(ushort4*)&hA_lo[(size_t)j*4] = z;
    } else {
      int j=i-T8;
      *(float4*)&c[(size_t)j*4] = make_float4(0.f,0.f,0.f,0.f);
    }
  }
}

// ---------------------------------------------------------------------------
// proj GEMM, pure fp16, BM=BN=128, XCD-aware 1D grid (2048 blocks),
// reg-staged with 1-ahead prefetch (R11-proven).
// ---------------------------------------------------------------------------
__global__ __launch_bounds__(256) void gemm_proj16(
    const u16* __restrict__ Ah, const u16* __restrict__ Bh,
    u16* __restrict__ projh)
{
  extern __shared__ char smem[];
  constexpr int STR = 40;
  short* As = (short*)smem;                  // [128][STR]
  short* Bs = As + 128*STR;
  const int tid=threadIdx.x;
  const int n = blockIdx.x;
  const int x = n & 7, q = n >> 3;
  const int bn = (q & 3) * 128;
  const int bm = ((q >> 2)*8 + x) * 128;
  const int w=tid>>6, lane=tid&63, wr=w>>1, wc=w&1;

  f32x4v acc[4][4];
#pragma unroll
  for (int i=0;i<4;i++)
#pragma unroll
    for (int j=0;j<4;j++) acc[i][j] = (f32x4v){0.f,0.f,0.f,0.f};

  u16x8 ra[2], rb[2];
  auto load = [&](int it){
    const int kk = it<<5;
#pragma unroll
    for (int L=0; L<2; L++){
      int t=L*256+tid, row=t>>2, c=(t&3)*8;
      ra[L] = *(const u16x8*)&Ah[(size_t)(bm+row)*512 + kk + c];
      rb[L] = *(const u16x8*)&Bh[(size_t)(bn+row)*512 + kk + c];
    }
  };
  load(0);

  for (int it=0; it<16; ++it){
    __syncthreads();
#pragma unroll
    for (int L=0; L<2; L++){
      int t=L*256+tid, row=t>>2, c=(t&3)*8;
      *(u16x8*)&As[row*STR+c] = ra[L];
      *(u16x8*)&Bs[row*STR+c] = rb[L];
    }
    if (it+1 < 16) load(it+1);
    __syncthreads();
    const int koff = (lane>>4)*8, mrow = lane&15;
#pragma unroll
    for (int i=0;i<4;i++)
#pragma unroll
      for (int j=0;j<4;j++){
        f16x8v af = *(const f16x8v*)&As[(wr*64+i*16+mrow)*STR + koff];
        f16x8v bf = *(const f16x8v*)&Bs[(wc*64+j*16+mrow)*STR + koff];
        acc[i][j] = __builtin_amdgcn_mfma_f32_16x16x32_f16(af, bf, acc[i][j], 0,0,0);
      }
  }

  // epilogue: fp16 out via LDS bounce
  const int r0 = (lane>>4)*4, cn = lane&15;
  __syncthreads();
  u16* Ts = (u16*)smem;   // [128][128]
#pragma unroll
  for (int i=0;i<4;i++)
#pragma unroll
    for (int j=0;j<4;j++)
#pragma unroll
      for (int r=0;r<4;r++)
        Ts[(wr*64+i*16+r0+r)*128 + wc*64+j*16+cn] = f2h_u(acc[i][j][r]);
  __syncthreads();
#pragma unroll
  for (int q2=0;q2<8;q2++){
    int idx = q2*256 + tid;
    int row = idx>>4, c8 = (idx&15)*8;
    *(float4*)&projh[(size_t)(bm+row)*512 + bn + c8] = *(const float4*)&Ts[row*128 + c8];
  }
}

// ---------------------------------------------------------------------------
// bf16 MFMA GEMM 64x64, K=512, FUSED bf16x2 3-pass (single K-sweep):
// per BK=64 chunk stage Ah/Al/Bh/Bl tiles once, issue hi*hi + hi*lo + lo*hi.
// 8 chunks, register ping-pong with 1-ahead prefetch.  Barriers /3 vs 3-pass.
// MODE 0: fp32 out + col-bias.  MODE 2: generator out (m->(s,b), n<38, +bias2).
// ---------------------------------------------------------------------------
template<int MODE>
__global__ __launch_bounds__(256) void gemm_bf64(
    const u16* __restrict__ Ah, const u16* __restrict__ Al, int lda,
    const u16* __restrict__ Bh, const u16* __restrict__ Bl, int ldb,
    float* __restrict__ Cout, int ldc, const float* __restrict__ bias2)
{
  constexpr int STR = 72;                  // 64 + 8 pad
  __shared__ short Ash[64*STR];
  __shared__ short Asl[64*STR];
  __shared__ short Bsh[64*STR];
  __shared__ short Bsl[64*STR];
  const int tid=threadIdx.x, lane=tid&63, w=tid>>6, wr=w>>1, wc=w&1;
  const int bm=blockIdx.y*64, bn=blockIdx.x*64;
  const int mrow=lane&15, koff=(lane>>4)*8;
  const int srow=tid>>2, scc=(tid&3)*8;

  f32x4v acc[2][2];
#pragma unroll
  for (int i=0;i<2;i++)
#pragma unroll
    for (int j=0;j<2;j++) acc[i][j] = (f32x4v){0.f,0.f,0.f,0.f};

  u16x8 r0[8], r1[8];                      // {Ah,Ah+32,Al,Al+32,Bh,Bh+32,Bl,Bl+32}
  auto loadTo = [&](u16x8* r, int it){
    const int kk = it<<6;
    const size_t ao = (size_t)(bm+srow)*lda + kk + scc;
    const size_t bo = (size_t)(bn+srow)*ldb + kk + scc;
    r[0] = *(const u16x8*)&Ah[ao];   r[1] = *(const u16x8*)&Ah[ao+32];
    r[2] = *(const u16x8*)&Al[ao];   r[3] = *(const u16x8*)&Al[ao+32];
    r[4] = *(const u16x8*)&Bh[bo];   r[5] = *(const u16x8*)&Bh[bo+32];
    r[6] = *(const u16x8*)&Bl[bo];   r[7] = *(const u16x8*)&Bl[bo+32];
  };
  auto stage = [&](const u16x8* r){
    *(u16x8*)&Ash[srow*STR+scc]    = r[0];
    *(u16x8*)&Ash[srow*STR+scc+32] = r[1];
    *(u16x8*)&Asl[srow*STR+scc]    = r[2];
    *(u16x8*)&Asl[srow*STR+scc+32] = r[3];
    *(u16x8*)&Bsh[srow*STR+scc]    = r[4];
    *(u16x8*)&Bsh[srow*STR+scc+32] = r[5];
    *(u16x8*)&Bsl[srow*STR+scc]    = r[6];
    *(u16x8*)&Bsl[srow*STR+scc+32] = r[7];
  };
  auto compute = [&](){
#pragma unroll
    for (int i=0;i<2;i++)
#pragma unroll
      for (int j=0;j<2;j++)
#pragma unroll
        for (int ks=0;ks<2;ks++){
          const int ar = (wr*32+i*16+mrow)*STR + ks*32 + koff;
          const int br = (wc*32+j*16+mrow)*STR + ks*32 + koff;
          bf16x8v ah = *(const bf16x8v*)&Ash[ar];
          bf16x8v al = *(const bf16x8v*)&Asl[ar];
          bf16x8v bh = *(const bf16x8v*)&Bsh[br];
          bf16x8v bl = *(const bf16x8v*)&Bsl[br];
          acc[i][j] = __builtin_amdgcn_mfma_f32_16x16x32_bf16(ah, bh, acc[i][j], 0,0,0);
          acc[i][j] = __builtin_amdgcn_mfma_f32_16x16x32_bf16(ah, bl, acc[i][j], 0,0,0);
          acc[i][j] = __builtin_amdgcn_mfma_f32_16x16x32_bf16(al, bh, acc[i][j], 0,0,0);
        }
  };

  loadTo(r0, 0);
  for (int it=0; it<8; it+=2){
    __syncthreads();
    stage(r0);
    if (it+1 < 8) loadTo(r1, it+1);
    __syncthreads();
    compute();
    if (it+1 >= 8) break;
    __syncthreads();
    stage(r1);
    if (it+2 < 8) loadTo(r0, it+2);
    __syncthreads();
    compute();
  }

  const int r0i = (lane>>4)*4, cn = lane&15;
  if constexpr (MODE==2){
#pragma unroll
    for (int i=0;i<2;i++)
#pragma unroll
      for (int j=0;j<2;j++)
#pragma unroll
        for (int r=0;r<4;r++){
          int m = bm + wr*32 + i*16 + r0i + r;       // m = s*512 + b
          int n2 = bn + wc*32 + j*16 + cn;
          if (n2 < MID_){
            int s = m >> 9, b = m & 511;
            Cout[((size_t)b*S_ + s)*MID_ + n2] = acc[i][j][r] + bias2[n2];
          }
        }
  } else {
#pragma unroll
    for (int i=0;i<2;i++)
#pragma unroll
      for (int j=0;j<2;j++)
#pragma unroll
        for (int r=0;r<4;r++){
          int row = bm + wr*32 + i*16 + r0i + r;
          int col = bn + wc*32 + j*16 + cn;
          float v = acc[i][j][r];
          if (bias2) v += bias2[col];
          Cout[(size_t)row*ldc + col] = v;
        }
  }
}

// ---------------------------------------------------------------------------
// Fused attention, 1024 threads (16 waves)  (R15-proven version).
// ---------------------------------------------------------------------------
__global__ __launch_bounds__(1024) void attn_kernel(
    const u16* __restrict__ projh, const float* __restrict__ combo,
    const float* __restrict__ Wscore, const u16* __restrict__ bHh,
    u16* __restrict__ ctx_hi, u16* __restrict__ ctx_lo)
{
  __shared__ float s_e[T_];
  __shared__ float s_part[16][D_];
  const int tid=threadIdx.x, b=blockIdx.x, wave=tid>>6, lane=tid&63;

  float pv[8], wv[8];
  {
    const float* pprow = combo + (size_t)b*2560;
    float4 p0=*(const float4*)&pprow[lane*8], p1=*(const float4*)&pprow[lane*8+4];
    float4 w0=*(const float4*)&Wscore[lane*8], w1=*(const float4*)&Wscore[lane*8+4];
    pv[0]=p0.x;pv[1]=p0.y;pv[2]=p0.z;pv[3]=p0.w;pv[4]=p1.x;pv[5]=p1.y;pv[6]=p1.z;pv[7]=p1.w;
    wv[0]=w0.x;wv[1]=w0.y;wv[2]=w0.z;wv[3]=w0.w;wv[4]=w1.x;wv[5]=w1.y;wv[6]=w1.z;wv[7]=w1.w;
  }
  // e-phase: wave w owns t = w + 16k, k=0..7.  Two 4-row batches, loads of
  // both batches issued before compute of the first (8 loads in flight).
  {
    const u16* base = projh + (size_t)b*T_*H_ + lane*8;
    u16x8 rA[4], rB[4];
#pragma unroll
    for (int k=0;k<4;k++) rA[k] = *(const u16x8*)(base + (size_t)(wave+16*k)*H_);
#pragma unroll
    for (int k=0;k<4;k++) rB[k] = *(const u16x8*)(base + (size_t)(wave+16*(k+4))*H_);
#pragma unroll
    for (int k=0;k<4;k++){
      float acc = 0.f;
#pragma unroll
      for (int j=0;j<8;j++) acc += wv[j]*fast_tanh(h2f_u(rA[k][j]) + pv[j]);
#pragma unroll
      for (int o=32;o>0;o>>=1) acc += __shfl_down(acc,o);
      if (lane==0) s_e[wave+16*k] = acc;
    }
#pragma unroll
    for (int k=0;k<4;k++){
      float acc = 0.f;
#pragma unroll
      for (int j=0;j<8;j++) acc += wv[j]*fast_tanh(h2f_u(rB[k][j]) + pv[j]);
#pragma unroll
      for (int o=32;o>0;o>>=1) acc += __shfl_down(acc,o);
      if (lane==0) s_e[wave+16*(k+4)] = acc;
    }
  }
  __syncthreads();
  // single-wave softmax, no max subtraction (e bounded, exp safe in fp32)
  if (wave==0){
    float p0 = __expf(s_e[lane]), p1 = __expf(s_e[lane+64]);
    float ss = p0 + p1;
#pragma unroll
    for (int o=32;o>0;o>>=1) ss += __shfl_xor(ss,o);
    const float inv = __builtin_amdgcn_rcpf(ss);
    s_e[lane]    = p0*inv;
    s_e[lane+64] = p1*inv;
  }
  __syncthreads();

  // context: wave w covers t in [8w, 8w+8); all 8 rows loaded upfront
  const int d0 = lane*8;
  float a[8] = {0,0,0,0,0,0,0,0};
  {
    const u16* base = bHh + (size_t)b*T_*D_ + d0;
    const int t0 = wave*8;
    u16x8 rr[8];
#pragma unroll
    for (int r=0;r<8;r++) rr[r] = *(const u16x8*)(base + (size_t)(t0+r)*D_);
#pragma unroll
    for (int r=0;r<8;r++){
      const float al = s_e[t0+r];
#pragma unroll
      for (int j=0;j<8;j++) a[j] += al*h2f_u(rr[r][j]);
    }
  }
  *(float4*)&s_part[wave][d0]   = make_float4(a[0],a[1],a[2],a[3]);
  *(float4*)&s_part[wave][d0+4] = make_float4(a[4],a[5],a[6],a[7]);
  __syncthreads();
  if (tid < D_){
    float vv = s_part[0][tid];
#pragma unroll
    for (int q=1;q<16;q++) vv += s_part[q][tid];
    u16 hh=f2bf_rn(vv), ll=f2bf_rn(vv-bf2f(hh));
    ctx_hi[(size_t)b*512 + tid] = hh;
    ctx_lo[(size_t)b*512 + tid] = ll;
  }
}

// ---------------------------------------------------------------------------
// Fused gates GEMM + LSTM pointwise, FUSED 3-pass single K-sweep:
// per BK=64 chunk stage Bh/Bl tiles, load Ah/Al frags direct from global,
// issue hi*hi + hi*lo + lo*hi.  8 chunks, ping-pong prefetch.
// ---------------------------------------------------------------------------
__global__ __launch_bounds__(256) void gates_lstm(
    const u16* __restrict__ Ah, const u16* __restrict__ Al,     // [512][512]
    const u16* __restrict__ Bh, const u16* __restrict__ Bl,     // [2048][512]
    const float* __restrict__ combo,                            // [512][2560]
    const float* __restrict__ WmT, const float* __restrict__ WbT,
    const int* __restrict__ midtok, const int* __restrict__ bottok,
    float* __restrict__ c,
    u16* __restrict__ hA_hi, u16* __restrict__ hA_lo,
    u16* __restrict__ hid_hi, u16* __restrict__ hid_lo, int s)
{
  constexpr int STR = 72;
  __shared__ short Bsh[64*STR];
  __shared__ short Bsl[64*STR];
  const int tid=threadIdx.x, lane=tid&63, w=tid>>6;
  const int j0 = blockIdx.x*16, bm = blockIdx.y*64;
  const int mrow=lane&15, koff=(lane>>4)*8;
  const int arow = bm + w*16 + mrow;
  const int srow = tid>>2, scc=(tid&3)*8;
  const int sbrow = (srow>>4)*512 + j0 + (srow&15);

  f32x4v acc[4];
#pragma unroll
  for (int f=0;f<4;f++) acc[f] = (f32x4v){0.f,0.f,0.f,0.f};

  u16x8 rb0[4], rb1[4];                 // {Bh,Bh+32,Bl,Bl+32}
  bf16x8v a0[4], a1[4];                 // {Ah ks0, Ah ks1, Al ks0, Al ks1}
  auto loadB = [&](u16x8* r, int it){
    const int kk = it<<6;
    const size_t bo = (size_t)sbrow*512 + kk + scc;
    r[0] = *(const u16x8*)&Bh[bo];   r[1] = *(const u16x8*)&Bh[bo+32];
    r[2] = *(const u16x8*)&Bl[bo];   r[3] = *(const u16x8*)&Bl[bo+32];
  };
  auto loadA = [&](bf16x8v* a, int it){
    const int kk = it<<6;
    const size_t ao = (size_t)arow*512 + kk + koff;
    a[0] = *(const bf16x8v*)&Ah[ao];  a[1] = *(const bf16x8v*)&Ah[ao+32];
    a[2] = *(const bf16x8v*)&Al[ao];  a[3] = *(const bf16x8v*)&Al[ao+32];
  };
  auto stage = [&](const u16x8* r){
    *(u16x8*)&Bsh[srow*STR+scc]    = r[0];
    *(u16x8*)&Bsh[srow*STR+scc+32] = r[1];
    *(u16x8*)&Bsl[srow*STR+scc]    = r[2];
    *(u16x8*)&Bsl[srow*STR+scc+32] = r[3];
  };
  auto compute = [&](const bf16x8v* a){
#pragma unroll
    for (int f=0;f<4;f++)
#pragma unroll
      for (int ks=0;ks<2;ks++){
        const int br = (f*16+mrow)*STR + ks*32 + koff;
        bf16x8v bh = *(const bf16x8v*)&Bsh[br];
        bf16x8v bl = *(const bf16x8v*)&Bsl[br];
        acc[f] = __builtin_amdgcn_mfma_f32_16x16x32_bf16(a[ks],   bh, acc[f], 0,0,0);
        acc[f] = __builtin_amdgcn_mfma_f32_16x16x32_bf16(a[ks],   bl, acc[f], 0,0,0);
        acc[f] = __builtin_amdgcn_mfma_f32_16x16x32_bf16(a[ks+2], bh, acc[f], 0,0,0);
      }
  };

  loadB(rb0, 0); loadA(a0, 0);
  for (int it=0; it<8; it+=2){
    __syncthreads();
    stage(rb0);
    if (it+1 < 8){ loadB(rb1, it+1); loadA(a1, it+1); }
    __syncthreads();
    compute(a0);
    if (it+1 >= 8) break;
    __syncthreads();
    stage(rb1);
    if (it+2 < 8){ loadB(rb0, it+2); loadA(a0, it+2); }
    __syncthreads();
    compute(a1);
  }

  // epilogue: lane holds gates f=0..3 for rows r0..r0+3 (b), col jj
  const int r0=(lane>>4)*4, jj=lane&15, j=j0+jj;
#pragma unroll
  for (int r=0;r<4;r++){
    const int b = bm + w*16 + r0 + r;
    const int mt = midtok[b*26 + s];
    const int bt = bottok[b*26 + s];
    const float* wm = WmT + (size_t)mt*2048;
    const float* wb = WbT + (size_t)bt*2048;
    const float* cb = combo + (size_t)b*2560 + 512;
    float ig = acc[0][r] + cb[j       ] + wm[j       ] + wb[j       ];
    float fg = acc[1][r] + cb[512 + j ] + wm[512 + j ] + wb[512 + j ];
    float gg = acc[2][r] + cb[1024 + j] + wm[1024 + j] + wb[1024 + j];
    float og = acc[3][r] + cb[1536 + j] + wm[1536 + j] + wb[1536 + j];
    ig = fast_sig(ig);
    fg = fast_sig(fg);
    gg = fast_tanh(gg);
    og = fast_sig(og);
    const size_t ci = (size_t)b*512 + j;
    const float cn = fg*c[ci] + ig*gg;
    const float hn = og*fast_tanh(cn);
    c[ci] = cn;
    u16 hh = f2bf_rn(hn), hl = f2bf_rn(hn - bf2f(hh));
    hA_hi[ci] = hh;
    hA_lo[ci] = hl;
    hid_hi[((size_t)s*512 + b)*512 + j] = hh;
    hid_lo[((size_t)s*512 + b)*512 + j] = hl;
  }
}

extern "C" void kernel_launch(void* const* d_in, const int* in_sizes, int n_in,
                              void* d_out, int out_size, void* d_ws, size_t ws_size,
                              hipStream_t stream) {
  const float* bH   = (const float*)d_in[0];
  const int*   midt = (const int*)  d_in[1];
  const int*   bott = (const int*)  d_in[2];
  const float* Wi2h = (const float*)d_in[3];
  const float* Wh2h = (const float*)d_in[4];
  const float* bh2h = (const float*)d_in[5];
  const float* Wsc  = (const float*)d_in[6];
  const float* Wih  = (const float*)d_in[7];
  const float* Whh  = (const float*)d_in[8];
  const float* bih  = (const float*)d_in[9];
  const float* bhh  = (const float*)d_in[10];
  const float* Wgen = (const float*)d_in[11];
  const float* bgen = (const float*)d_in[12];
  float* out = (float*)d_out;

  char* wp = (char*)d_ws;
  u16* projh   = (u16*)wp; wp += (size_t)B_*T_*H_*2;      // 67.1 MB fp16
  u16* bHh     = (u16*)wp; wp += (size_t)B_*T_*D_*2;      // 67.1 MB fp16
  u16* Bh2_hi  = (u16*)wp; wp += (size_t)2560*512*2;      // [W_h2h|W_hh] planes
  u16* Bh2_lo  = (u16*)wp; wp += (size_t)2560*512*2;
  u16* Bih_hi  = (u16*)wp; wp += (size_t)2048*512*2;      // W_ih[:, :512] planes
  u16* Bih_lo  = (u16*)wp; wp += (size_t)2048*512*2;
  u16* Wi2h_h  = (u16*)wp; wp += (size_t)512*512*2;       // fp16
  u16* Wg_hi   = (u16*)wp; wp += (size_t)64*512*2;
  u16* Wg_lo   = (u16*)wp; wp += (size_t)64*512*2;
  u16* ctx_hi  = (u16*)wp; wp += (size_t)B_*512*2;
  u16* ctx_lo  = (u16*)wp; wp += (size_t)B_*512*2;
  u16* hA_hi   = (u16*)wp; wp += (size_t)B_*512*2;
  u16* hA_lo   = (u16*)wp; wp += (size_t)B_*512*2;
  u16* hid_hi  = (u16*)wp; wp += (size_t)S_*B_*H_*2;      // 13.6 MB
  u16* hid_lo  = (u16*)wp; wp += (size_t)S_*B_*H_*2;
  float* combo = (float*)wp; wp += (size_t)B_*2560*4;     // 5.2 MB
  float* c     = (float*)wp; wp += (size_t)B_*H_*4;
  float* bcombF= (float*)wp; wp += (size_t)2560*4;
  float* WmT   = (float*)wp; wp += (size_t)MID_*2048*4;
  float* WbT   = (float*)wp; wp += (size_t)BOT_*2048*4;
  if ((size_t)(wp - (char*)d_ws) > ws_size) return;  // fail loudly

  setup_all<<<4096, 256, 0, stream>>>(
      bH, Wi2h, Wh2h, Whh, Wih, Wgen, bh2h, bih, bhh,
      bHh, Wi2h_h, Bh2_hi, Bh2_lo, Bih_hi, Bih_lo, Wg_hi, Wg_lo,
      WmT, WbT, bcombF, hA_hi, hA_lo, c);

  // proj = fp16( bHh @ Wi2h^T ), pure fp16, XCD-aware 1D grid
  gemm_proj16<<<2048, 256, 32768, stream>>>(bHh, Wi2h_h, projh);

  for (int s=0; s<S_; ++s){
    // combo = h @ [W_h2h | W_hh]^T + [b_h2h | b_ih+b_hh]  (fused bf16x2)
    gemm_bf64<0><<<dim3(40,8), 256, 0, stream>>>(
        hA_hi, hA_lo, 512, Bh2_hi, Bh2_lo, 512,
        combo, 2560, bcombF);
    attn_kernel<<<B_, 1024, 0, stream>>>(
        projh, combo, Wsc, bHh, ctx_hi, ctx_lo);
    gates_lstm<<<dim3(32,8), 256, 0, stream>>>(
        ctx_hi, ctx_lo, Bih_hi, Bih_lo, combo, WmT, WbT,
        midt, bott, c, hA_hi, hA_lo,
        hid_hi, hid_lo, s);
  }

  // out = hid @ W_gen^T + b_gen  (fused bf16x2), M = S*B = 13312
  gemm_bf64<2><<<dim3(1,208), 256, 0, stream>>>(
      hid_hi, hid_lo, 512, Wg_hi, Wg_lo, 512,
      out, 0, bgen);
}

// Round 17
// 1326.710 us; speedup vs baseline: 1.3696x; 1.0045x over previous
//
#include <hip/hip_runtime.h>
#include <hip/hip_bf16.h>
#include <hip/hip_fp16.h>
#include <cstdint>
#include <cstddef>

#define B_   512
#define T_   128
#define D_   512
#define H_   512
#define MID_ 38
#define BOT_ 38
#define S_   26
#define XL_  588   // D + MID + BOT = W_ih row length

typedef unsigned short u16;
typedef __attribute__((ext_vector_type(8))) short bf16x8v;
typedef __attribute__((ext_vector_type(8))) _Float16 f16x8v;
typedef __attribute__((ext_vector_type(8))) unsigned short u16x8;
typedef __attribute__((ext_vector_type(4))) float f32x4v;

__device__ __forceinline__ u16 f2bf_rn(float f){
  unsigned u = __float_as_uint(f);
  return (u16)((u + 0x7fffu + ((u>>16)&1u)) >> 16);
}
__device__ __forceinline__ float bf2f(u16 v){ return __uint_as_float(((unsigned)v)<<16); }
__device__ __forceinline__ u16 f2h_u(float f){ return __half_as_ushort(__float2half(f)); }
__device__ __forceinline__ float h2f_u(u16 u){ return __half2float(__ushort_as_half(u)); }

// branch-free fast transcendentals (v_exp_f32 + v_rcp_f32, ~1e-6 rel err)
__device__ __forceinline__ float fast_tanh(float x){
  return 1.0f - 2.0f*__builtin_amdgcn_rcpf(__expf(2.0f*x) + 1.0f);
}
__device__ __forceinline__ float fast_sig(float x){
  return __builtin_amdgcn_rcpf(1.0f + __expf(-x));
}

// ---------------------------------------------------------------------------
// One-shot setup: bH->fp16, weight conversions, token tables, bias combine,
// h/c zero-init.  Flat quad-index space, grid-stride.
// ---------------------------------------------------------------------------
__device__ __forceinline__ void cvt_hilo4(const float* src, u16* hi, u16* lo){
  float4 v = *(const float4*)src;
  ushort4 h, l;
  h.x=f2bf_rn(v.x); h.y=f2bf_rn(v.y); h.z=f2bf_rn(v.z); h.w=f2bf_rn(v.w);
  l.x=f2bf_rn(v.x-bf2f(h.x)); l.y=f2bf_rn(v.y-bf2f(h.y));
  l.z=f2bf_rn(v.z-bf2f(h.z)); l.w=f2bf_rn(v.w-bf2f(h.w));
  *(ushort4*)hi = h; *(ushort4*)lo = l;
}

__global__ __launch_bounds__(256) void setup_all(
    const float* __restrict__ bH,
    const float* __restrict__ Wi2h, const float* __restrict__ Wh2h,
    const float* __restrict__ Whh,  const float* __restrict__ Wih,
    const float* __restrict__ Wgen, const float* __restrict__ bh2h,
    const float* __restrict__ bih,  const float* __restrict__ bhh,
    u16* __restrict__ bHh,
    u16* __restrict__ Wi2h_h, u16* __restrict__ Bh2_hi, u16* __restrict__ Bh2_lo,
    u16* __restrict__ Bih_hi, u16* __restrict__ Bih_lo,
    u16* __restrict__ Wg_hi,  u16* __restrict__ Wg_lo,
    float* __restrict__ WmT, float* __restrict__ WbT, float* __restrict__ bcombF,
    u16* __restrict__ hA_hi, u16* __restrict__ hA_lo, float* __restrict__ c)
{
  const int T0 = 8388608;               // bH -> fp16 (65536 rows x 128 quads)
  const int T1 = T0+65536;              // Wi2h -> fp16
  const int T2 = T1+65536;              // Wh2h -> Bh2[0:512] hi/lo
  const int T3 = T2+262144;             // Whh  -> Bh2[512:2560]
  const int T4 = T3+262144;             // Wih[:, :512] -> Bih
  const int T5 = T4+8192;               // Wgen -> Wg (pad 64 rows)
  const int T6 = T5+19456;              // token tables (38*512 quads)
  const int T7 = T6+640;                // bcombF
  const int T8 = T7+65536;              // hA hi/lo zero (ushort4 each)
  const int T9 = T8+65536;              // c zero (float4)
  for (int i = blockIdx.x*256 + threadIdx.x; i < T9; i += gridDim.x*256){
    if (i < T0){
      int row=i>>7, c4=(i&127)*4;
      float4 v = *(const float4*)&bH[(size_t)row*512 + c4];
      ushort4 h; h.x=f2h_u(v.x); h.y=f2h_u(v.y); h.z=f2h_u(v.z); h.w=f2h_u(v.w);
      *(ushort4*)&bHh[(size_t)row*512 + c4] = h;
    } else if (i < T1){
      int j=i-T0, row=j>>7, c4=(j&127)*4;
      float4 v = *(const float4*)&Wi2h[(size_t)row*512 + c4];
      ushort4 h; h.x=f2h_u(v.x); h.y=f2h_u(v.y); h.z=f2h_u(v.z); h.w=f2h_u(v.w);
      *(ushort4*)&Wi2h_h[(size_t)row*512 + c4] = h;
    } else if (i < T2){
      int j=i-T1, row=j>>7, c4=(j&127)*4;
      cvt_hilo4(&Wh2h[(size_t)row*512+c4], &Bh2_hi[(size_t)row*512+c4], &Bh2_lo[(size_t)row*512+c4]);
    } else if (i < T3){
      int j=i-T2, row=j>>7, c4=(j&127)*4;
      cvt_hilo4(&Whh[(size_t)row*512+c4],
                &Bh2_hi[(size_t)(512+row)*512+c4], &Bh2_lo[(size_t)(512+row)*512+c4]);
    } else if (i < T4){
      int j=i-T3, row=j>>7, c4=(j&127)*4;
      cvt_hilo4(&Wih[(size_t)row*XL_+c4], &Bih_hi[(size_t)row*512+c4], &Bih_lo[(size_t)row*512+c4]);
    } else if (i < T5){
      int j=i-T4, row=j>>7, c4=(j&127)*4;
      float4 v = make_float4(0.f,0.f,0.f,0.f);
      if (row < MID_) v = *(const float4*)&Wgen[(size_t)row*512 + c4];
      ushort4 h, l;
      h.x=f2bf_rn(v.x); h.y=f2bf_rn(v.y); h.z=f2bf_rn(v.z); h.w=f2bf_rn(v.w);
      l.x=f2bf_rn(v.x-bf2f(h.x)); l.y=f2bf_rn(v.y-bf2f(h.y));
      l.z=f2bf_rn(v.z-bf2f(h.z)); l.w=f2bf_rn(v.w-bf2f(h.w));
      *(ushort4*)&Wg_hi[(size_t)row*512+c4] = h;
      *(ushort4*)&Wg_lo[(size_t)row*512+c4] = l;
    } else if (i < T6){
      int j=i-T5;                    // 38*512
      int cc=j>>9, jq=j&511;
#pragma unroll
      for (int u=0;u<4;u++){
        int jj=jq*4+u;
        WmT[(size_t)cc*2048+jj] = Wih[(size_t)jj*XL_ + 512 + cc];
        WbT[(size_t)cc*2048+jj] = Wih[(size_t)jj*XL_ + 512 + MID_ + cc];
      }
    } else if (i < T7){
      int j=(i-T6)*4;
#pragma unroll
      for (int u=0;u<4;u++){
        int k=j+u;
        if (k < 512) bcombF[k] = bh2h[k];
        else if (k < 2560) bcombF[k] = bih[k-512] + bhh[k-512];
      }
    } else if (i < T8){
      int j=i-T7;
      ushort4 z = {0,0,0,0};
      *(ushort4*)&hA_hi[(size_t)j*4] = z;
      *(ushort4*)&hA_lo[(size_t)j*4] = z;
    } else {
      int j=i-T8;
      *(float4*)&c[(size_t)j*4] = make_float4(0.f,0.f,0.f,0.f);
    }
  }
}

// ---------------------------------------------------------------------------
// proj GEMM, pure fp16, BM=BN=128, BK=64, STR=72 pad, register ping-pong
// with 1-ahead prefetch (gemm_bf64-proven loop), XCD-aware 1D grid.
// A = bHh fp16, B = Wi2h fp16.  C = fp16 projh via LDS bounce.
// ---------------------------------------------------------------------------
__global__ __launch_bounds__(256) void gemm_proj16(
    const u16* __restrict__ Ah, const u16* __restrict__ Bh,
    u16* __restrict__ projh)
{
  extern __shared__ char smem[];
  constexpr int STR = 72;
  short* As = (short*)smem;                  // [128][STR]
  short* Bs = As + 128*STR;                  // [128][STR]
  const int tid=threadIdx.x;
  const int n = blockIdx.x;
  const int x = n & 7, q = n >> 3;
  const int bn = (q & 3) * 128;
  const int bm = ((q >> 2)*8 + x) * 128;
  const int w=tid>>6, lane=tid&63, wr=w>>1, wc=w&1;
  const int srow = tid>>1, shalf = (tid&1)*32;   // 2 threads per row, 32 cols each

  f32x4v acc[4][4];
#pragma unroll
  for (int i=0;i<4;i++)
#pragma unroll
    for (int j=0;j<4;j++) acc[i][j] = (f32x4v){0.f,0.f,0.f,0.f};

  u16x8 r0[8], r1[8];            // {A q0..q3, B q0..q3}
  auto loadTo = [&](u16x8* r, int it){
    const int kk = it<<6;
    const size_t ao = (size_t)(bm+srow)*512 + kk + shalf;
    const size_t bo = (size_t)(bn+srow)*512 + kk + shalf;
#pragma unroll
    for (int qq=0;qq<4;qq++) r[qq]   = *(const u16x8*)&Ah[ao + qq*8];
#pragma unroll
    for (int qq=0;qq<4;qq++) r[4+qq] = *(const u16x8*)&Bh[bo + qq*8];
  };
  auto stage = [&](const u16x8* r){
#pragma unroll
    for (int qq=0;qq<4;qq++) *(u16x8*)&As[srow*STR + shalf + qq*8] = r[qq];
#pragma unroll
    for (int qq=0;qq<4;qq++) *(u16x8*)&Bs[srow*STR + shalf + qq*8] = r[4+qq];
  };
  const int koff = (lane>>4)*8, mrow = lane&15;
  auto compute = [&](){
#pragma unroll
    for (int ks=0;ks<2;ks++)
#pragma unroll
      for (int i=0;i<4;i++)
#pragma unroll
        for (int j=0;j<4;j++){
          f16x8v af = *(const f16x8v*)&As[(wr*64+i*16+mrow)*STR + ks*32 + koff];
          f16x8v bf = *(const f16x8v*)&Bs[(wc*64+j*16+mrow)*STR + ks*32 + koff];
          acc[i][j] = __builtin_amdgcn_mfma_f32_16x16x32_f16(af, bf, acc[i][j], 0,0,0);
        }
  };

  loadTo(r0, 0);
  for (int it=0; it<8; it+=2){
    __syncthreads();
    stage(r0);
    if (it+1 < 8) loadTo(r1, it+1);
    __syncthreads();
    compute();
    if (it+1 >= 8) break;
    __syncthreads();
    stage(r1);
    if (it+2 < 8) loadTo(r0, it+2);
    __syncthreads();
    compute();
  }

  // epilogue: fp16 out via LDS bounce
  const int r0i = (lane>>4)*4, cn = lane&15;
  __syncthreads();
  u16* Ts = (u16*)smem;   // [128][128] (32 KB, fits in 36.9 KB smem)
#pragma unroll
  for (int i=0;i<4;i++)
#pragma unroll
    for (int j=0;j<4;j++)
#pragma unroll
      for (int r=0;r<4;r++)
        Ts[(wr*64+i*16+r0i+r)*128 + wc*64+j*16+cn] = f2h_u(acc[i][j][r]);
  __syncthreads();
#pragma unroll
  for (int q2=0;q2<8;q2++){
    int idx = q2*256 + tid;
    int row = idx>>4, c8 = (idx&15)*8;
    *(float4*)&projh[(size_t)(bm+row)*512 + bn + c8] = *(const float4*)&Ts[row*128 + c8];
  }
}

// ---------------------------------------------------------------------------
// bf16 MFMA GEMM 64x64, K=512, FUSED bf16x2 3-pass (single K-sweep):
// per BK=64 chunk stage Ah/Al/Bh/Bl tiles once, issue hi*hi + hi*lo + lo*hi.
// 8 chunks, register ping-pong with 1-ahead prefetch.
// MODE 0: fp32 out + col-bias.  MODE 2: generator out (m->(s,b), n<38, +bias2).
// ---------------------------------------------------------------------------
template<int MODE>
__global__ __launch_bounds__(256) void gemm_bf64(
    const u16* __restrict__ Ah, const u16* __restrict__ Al, int lda,
    const u16* __restrict__ Bh, const u16* __restrict__ Bl, int ldb,
    float* __restrict__ Cout, int ldc, const float* __restrict__ bias2)
{
  constexpr int STR = 72;                  // 64 + 8 pad
  __shared__ short Ash[64*STR];
  __shared__ short Asl[64*STR];
  __shared__ short Bsh[64*STR];
  __shared__ short Bsl[64*STR];
  const int tid=threadIdx.x, lane=tid&63, w=tid>>6, wr=w>>1, wc=w&1;
  const int bm=blockIdx.y*64, bn=blockIdx.x*64;
  const int mrow=lane&15, koff=(lane>>4)*8;
  const int srow=tid>>2, scc=(tid&3)*8;

  f32x4v acc[2][2];
#pragma unroll
  for (int i=0;i<2;i++)
#pragma unroll
    for (int j=0;j<2;j++) acc[i][j] = (f32x4v){0.f,0.f,0.f,0.f};

  u16x8 r0[8], r1[8];                      // {Ah,Ah+32,Al,Al+32,Bh,Bh+32,Bl,Bl+32}
  auto loadTo = [&](u16x8* r, int it){
    const int kk = it<<6;
    const size_t ao = (size_t)(bm+srow)*lda + kk + scc;
    const size_t bo = (size_t)(bn+srow)*ldb + kk + scc;
    r[0] = *(const u16x8*)&Ah[ao];   r[1] = *(const u16x8*)&Ah[ao+32];
    r[2] = *(const u16x8*)&Al[ao];   r[3] = *(const u16x8*)&Al[ao+32];
    r[4] = *(const u16x8*)&Bh[bo];   r[5] = *(const u16x8*)&Bh[bo+32];
    r[6] = *(const u16x8*)&Bl[bo];   r[7] = *(const u16x8*)&Bl[bo+32];
  };
  auto stage = [&](const u16x8* r){
    *(u16x8*)&Ash[srow*STR+scc]    = r[0];
    *(u16x8*)&Ash[srow*STR+scc+32] = r[1];
    *(u16x8*)&Asl[srow*STR+scc]    = r[2];
    *(u16x8*)&Asl[srow*STR+scc+32] = r[3];
    *(u16x8*)&Bsh[srow*STR+scc]    = r[4];
    *(u16x8*)&Bsh[srow*STR+scc+32] = r[5];
    *(u16x8*)&Bsl[srow*STR+scc]    = r[6];
    *(u16x8*)&Bsl[srow*STR+scc+32] = r[7];
  };
  auto compute = [&](){
#pragma unroll
    for (int i=0;i<2;i++)
#pragma unroll
      for (int j=0;j<2;j++)
#pragma unroll
        for (int ks=0;ks<2;ks++){
          const int ar = (wr*32+i*16+mrow)*STR + ks*32 + koff;
          const int br = (wc*32+j*16+mrow)*STR + ks*32 + koff;
          bf16x8v ah = *(const bf16x8v*)&Ash[ar];
          bf16x8v al = *(const bf16x8v*)&Asl[ar];
          bf16x8v bh = *(const bf16x8v*)&Bsh[br];
          bf16x8v bl = *(const bf16x8v*)&Bsl[br];
          acc[i][j] = __builtin_amdgcn_mfma_f32_16x16x32_bf16(ah, bh, acc[i][j], 0,0,0);
          acc[i][j] = __builtin_amdgcn_mfma_f32_16x16x32_bf16(ah, bl, acc[i][j], 0,0,0);
          acc[i][j] = __builtin_amdgcn_mfma_f32_16x16x32_bf16(al, bh, acc[i][j], 0,0,0);
        }
  };

  loadTo(r0, 0);
  for (int it=0; it<8; it+=2){
    __syncthreads();
    stage(r0);
    if (it+1 < 8) loadTo(r1, it+1);
    __syncthreads();
    compute();
    if (it+1 >= 8) break;
    __syncthreads();
    stage(r1);
    if (it+2 < 8) loadTo(r0, it+2);
    __syncthreads();
    compute();
  }

  const int r0i = (lane>>4)*4, cn = lane&15;
  if constexpr (MODE==2){
#pragma unroll
    for (int i=0;i<2;i++)
#pragma unroll
      for (int j=0;j<2;j++)
#pragma unroll
        for (int r=0;r<4;r++){
          int m = bm + wr*32 + i*16 + r0i + r;       // m = s*512 + b
          int n2 = bn + wc*32 + j*16 + cn;
          if (n2 < MID_){
            int s = m >> 9, b = m & 511;
            Cout[((size_t)b*S_ + s)*MID_ + n2] = acc[i][j][r] + bias2[n2];
          }
        }
  } else {
#pragma unroll
    for (int i=0;i<2;i++)
#pragma unroll
      for (int j=0;j<2;j++)
#pragma unroll
        for (int r=0;r<4;r++){
          int row = bm + wr*32 + i*16 + r0i + r;
          int col = bn + wc*32 + j*16 + cn;
          float v = acc[i][j][r];
          if (bias2) v += bias2[col];
          Cout[(size_t)row*ldc + col] = v;
        }
  }
}

// ---------------------------------------------------------------------------
// Fused attention, 1024 threads (16 waves)  (R15-proven version).
// ---------------------------------------------------------------------------
__global__ __launch_bounds__(1024) void attn_kernel(
    const u16* __restrict__ projh, const float* __restrict__ combo,
    const float* __restrict__ Wscore, const u16* __restrict__ bHh,
    u16* __restrict__ ctx_hi, u16* __restrict__ ctx_lo)
{
  __shared__ float s_e[T_];
  __shared__ float s_part[16][D_];
  const int tid=threadIdx.x, b=blockIdx.x, wave=tid>>6, lane=tid&63;

  float pv[8], wv[8];
  {
    const float* pprow = combo + (size_t)b*2560;
    float4 p0=*(const float4*)&pprow[lane*8], p1=*(const float4*)&pprow[lane*8+4];
    float4 w0=*(const float4*)&Wscore[lane*8], w1=*(const float4*)&Wscore[lane*8+4];
    pv[0]=p0.x;pv[1]=p0.y;pv[2]=p0.z;pv[3]=p0.w;pv[4]=p1.x;pv[5]=p1.y;pv[6]=p1.z;pv[7]=p1.w;
    wv[0]=w0.x;wv[1]=w0.y;wv[2]=w0.z;wv[3]=w0.w;wv[4]=w1.x;wv[5]=w1.y;wv[6]=w1.z;wv[7]=w1.w;
  }
  // e-phase: wave w owns t = w + 16k, k=0..7.  Two 4-row batches, loads of
  // both batches issued before compute of the first (8 loads in flight).
  {
    const u16* base = projh + (size_t)b*T_*H_ + lane*8;
    u16x8 rA[4], rB[4];
#pragma unroll
    for (int k=0;k<4;k++) rA[k] = *(const u16x8*)(base + (size_t)(wave+16*k)*H_);
#pragma unroll
    for (int k=0;k<4;k++) rB[k] = *(const u16x8*)(base + (size_t)(wave+16*(k+4))*H_);
#pragma unroll
    for (int k=0;k<4;k++){
      float acc = 0.f;
#pragma unroll
      for (int j=0;j<8;j++) acc += wv[j]*fast_tanh(h2f_u(rA[k][j]) + pv[j]);
#pragma unroll
      for (int o=32;o>0;o>>=1) acc += __shfl_down(acc,o);
      if (lane==0) s_e[wave+16*k] = acc;
    }
#pragma unroll
    for (int k=0;k<4;k++){
      float acc = 0.f;
#pragma unroll
      for (int j=0;j<8;j++) acc += wv[j]*fast_tanh(h2f_u(rB[k][j]) + pv[j]);
#pragma unroll
      for (int o=32;o>0;o>>=1) acc += __shfl_down(acc,o);
      if (lane==0) s_e[wave+16*(k+4)] = acc;
    }
  }
  __syncthreads();
  // single-wave softmax, no max subtraction (e bounded, exp safe in fp32)
  if (wave==0){
    float p0 = __expf(s_e[lane]), p1 = __expf(s_e[lane+64]);
    float ss = p0 + p1;
#pragma unroll
    for (int o=32;o>0;o>>=1) ss += __shfl_xor(ss,o);
    const float inv = __builtin_amdgcn_rcpf(ss);
    s_e[lane]    = p0*inv;
    s_e[lane+64] = p1*inv;
  }
  __syncthreads();

  // context: wave w covers t in [8w, 8w+8); all 8 rows loaded upfront
  const int d0 = lane*8;
  float a[8] = {0,0,0,0,0,0,0,0};
  {
    const u16* base = bHh + (size_t)b*T_*D_ + d0;
    const int t0 = wave*8;
    u16x8 rr[8];
#pragma unroll
    for (int r=0;r<8;r++) rr[r] = *(const u16x8*)(base + (size_t)(t0+r)*D_);
#pragma unroll
    for (int r=0;r<8;r++){
      const float al = s_e[t0+r];
#pragma unroll
      for (int j=0;j<8;j++) a[j] += al*h2f_u(rr[r][j]);
    }
  }
  *(float4*)&s_part[wave][d0]   = make_float4(a[0],a[1],a[2],a[3]);
  *(float4*)&s_part[wave][d0+4] = make_float4(a[4],a[5],a[6],a[7]);
  __syncthreads();
  if (tid < D_){
    float vv = s_part[0][tid];
#pragma unroll
    for (int q=1;q<16;q++) vv += s_part[q][tid];
    u16 hh=f2bf_rn(vv), ll=f2bf_rn(vv-bf2f(hh));
    ctx_hi[(size_t)b*512 + tid] = hh;
    ctx_lo[(size_t)b*512 + tid] = ll;
  }
}

// ---------------------------------------------------------------------------
// Fused gates GEMM + LSTM pointwise, FUSED 3-pass single K-sweep (R16).
// ---------------------------------------------------------------------------
__global__ __launch_bounds__(256) void gates_lstm(
    const u16* __restrict__ Ah, const u16* __restrict__ Al,     // [512][512]
    const u16* __restrict__ Bh, const u16* __restrict__ Bl,     // [2048][512]
    const float* __restrict__ combo,                            // [512][2560]
    const float* __restrict__ WmT, const float* __restrict__ WbT,
    const int* __restrict__ midtok, const int* __restrict__ bottok,
    float* __restrict__ c,
    u16* __restrict__ hA_hi, u16* __restrict__ hA_lo,
    u16* __restrict__ hid_hi, u16* __restrict__ hid_lo, int s)
{
  constexpr int STR = 72;
  __shared__ short Bsh[64*STR];
  __shared__ short Bsl[64*STR];
  const int tid=threadIdx.x, lane=tid&63, w=tid>>6;
  const int j0 = blockIdx.x*16, bm = blockIdx.y*64;
  const int mrow=lane&15, koff=(lane>>4)*8;
  const int arow = bm + w*16 + mrow;
  const int srow = tid>>2, scc=(tid&3)*8;
  const int sbrow = (srow>>4)*512 + j0 + (srow&15);

  f32x4v acc[4];
#pragma unroll
  for (int f=0;f<4;f++) acc[f] = (f32x4v){0.f,0.f,0.f,0.f};

  u16x8 rb0[4], rb1[4];                 // {Bh,Bh+32,Bl,Bl+32}
  bf16x8v a0[4], a1[4];                 // {Ah ks0, Ah ks1, Al ks0, Al ks1}
  auto loadB = [&](u16x8* r, int it){
    const int kk = it<<6;
    const size_t bo = (size_t)sbrow*512 + kk + scc;
    r[0] = *(const u16x8*)&Bh[bo];   r[1] = *(const u16x8*)&Bh[bo+32];
    r[2] = *(const u16x8*)&Bl[bo];   r[3] = *(const u16x8*)&Bl[bo+32];
  };
  auto loadA = [&](bf16x8v* a, int it){
    const int kk = it<<6;
    const size_t ao = (size_t)arow*512 + kk + koff;
    a[0] = *(const bf16x8v*)&Ah[ao];  a[1] = *(const bf16x8v*)&Ah[ao+32];
    a[2] = *(const bf16x8v*)&Al[ao];  a[3] = *(const bf16x8v*)&Al[ao+32];
  };
  auto stage = [&](const u16x8* r){
    *(u16x8*)&Bsh[srow*STR+scc]    = r[0];
    *(u16x8*)&Bsh[srow*STR+scc+32] = r[1];
    *(u16x8*)&Bsl[srow*STR+scc]    = r[2];
    *(u16x8*)&Bsl[srow*STR+scc+32] = r[3];
  };
  auto compute = [&](const bf16x8v* a){
#pragma unroll
    for (int f=0;f<4;f++)
#pragma unroll
      for (int ks=0;ks<2;ks++){
        const int br = (f*16+mrow)*STR + ks*32 + koff;
        bf16x8v bh = *(const bf16x8v*)&Bsh[br];
        bf16x8v bl = *(const bf16x8v*)&Bsl[br];
        acc[f] = __builtin_amdgcn_mfma_f32_16x16x32_bf16(a[ks],   bh, acc[f], 0,0,0);
        acc[f] = __builtin_amdgcn_mfma_f32_16x16x32_bf16(a[ks],   bl, acc[f], 0,0,0);
        acc[f] = __builtin_amdgcn_mfma_f32_16x16x32_bf16(a[ks+2], bh, acc[f], 0,0,0);
      }
  };

  loadB(rb0, 0); loadA(a0, 0);
  for (int it=0; it<8; it+=2){
    __syncthreads();
    stage(rb0);
    if (it+1 < 8){ loadB(rb1, it+1); loadA(a1, it+1); }
    __syncthreads();
    compute(a0);
    if (it+1 >= 8) break;
    __syncthreads();
    stage(rb1);
    if (it+2 < 8){ loadB(rb0, it+2); loadA(a0, it+2); }
    __syncthreads();
    compute(a1);
  }

  // epilogue: lane holds gates f=0..3 for rows r0..r0+3 (b), col jj
  const int r0=(lane>>4)*4, jj=lane&15, j=j0+jj;
#pragma unroll
  for (int r=0;r<4;r++){
    const int b = bm + w*16 + r0 + r;
    const int mt = midtok[b*26 + s];
    const int bt = bottok[b*26 + s];
    const float* wm = WmT + (size_t)mt*2048;
    const float* wb = WbT + (size_t)bt*2048;
    const float* cb = combo + (size_t)b*2560 + 512;
    float ig = acc[0][r] + cb[j       ] + wm[j       ] + wb[j       ];
    float fg = acc[1][r] + cb[512 + j ] + wm[512 + j ] + wb[512 + j ];
    float gg = acc[2][r] + cb[1024 + j] + wm[1024 + j] + wb[1024 + j];
    float og = acc[3][r] + cb[1536 + j] + wm[1536 + j] + wb[1536 + j];
    ig = fast_sig(ig);
    fg = fast_sig(fg);
    gg = fast_tanh(gg);
    og = fast_sig(og);
    const size_t ci = (size_t)b*512 + j;
    const float cn = fg*c[ci] + ig*gg;
    const float hn = og*fast_tanh(cn);
    c[ci] = cn;
    u16 hh = f2bf_rn(hn), hl = f2bf_rn(hn - bf2f(hh));
    hA_hi[ci] = hh;
    hA_lo[ci] = hl;
    hid_hi[((size_t)s*512 + b)*512 + j] = hh;
    hid_lo[((size_t)s*512 + b)*512 + j] = hl;
  }
}

extern "C" void kernel_launch(void* const* d_in, const int* in_sizes, int n_in,
                              void* d_out, int out_size, void* d_ws, size_t ws_size,
                              hipStream_t stream) {
  const float* bH   = (const float*)d_in[0];
  const int*   midt = (const int*)  d_in[1];
  const int*   bott = (const int*)  d_in[2];
  const float* Wi2h = (const float*)d_in[3];
  const float* Wh2h = (const float*)d_in[4];
  const float* bh2h = (const float*)d_in[5];
  const float* Wsc  = (const float*)d_in[6];
  const float* Wih  = (const float*)d_in[7];
  const float* Whh  = (const float*)d_in[8];
  const float* bih  = (const float*)d_in[9];
  const float* bhh  = (const float*)d_in[10];
  const float* Wgen = (const float*)d_in[11];
  const float* bgen = (const float*)d_in[12];
  float* out = (float*)d_out;

  char* wp = (char*)d_ws;
  u16* projh   = (u16*)wp; wp += (size_t)B_*T_*H_*2;      // 67.1 MB fp16
  u16* bHh     = (u16*)wp; wp += (size_t)B_*T_*D_*2;      // 67.1 MB fp16
  u16* Bh2_hi  = (u16*)wp; wp += (size_t)2560*512*2;      // [W_h2h|W_hh] planes
  u16* Bh2_lo  = (u16*)wp; wp += (size_t)2560*512*2;
  u16* Bih_hi  = (u16*)wp; wp += (size_t)2048*512*2;      // W_ih[:, :512] planes
  u16* Bih_lo  = (u16*)wp; wp += (size_t)2048*512*2;
  u16* Wi2h_h  = (u16*)wp; wp += (size_t)512*512*2;       // fp16
  u16* Wg_hi   = (u16*)wp; wp += (size_t)64*512*2;
  u16* Wg_lo   = (u16*)wp; wp += (size_t)64*512*2;
  u16* ctx_hi  = (u16*)wp; wp += (size_t)B_*512*2;
  u16* ctx_lo  = (u16*)wp; wp += (size_t)B_*512*2;
  u16* hA_hi   = (u16*)wp; wp += (size_t)B_*512*2;
  u16* hA_lo   = (u16*)wp; wp += (size_t)B_*512*2;
  u16* hid_hi  = (u16*)wp; wp += (size_t)S_*B_*H_*2;      // 13.6 MB
  u16* hid_lo  = (u16*)wp; wp += (size_t)S_*B_*H_*2;
  float* combo = (float*)wp; wp += (size_t)B_*2560*4;     // 5.2 MB
  float* c     = (float*)wp; wp += (size_t)B_*H_*4;
  float* bcombF= (float*)wp; wp += (size_t)2560*4;
  float* WmT   = (float*)wp; wp += (size_t)MID_*2048*4;
  float* WbT   = (float*)wp; wp += (size_t)BOT_*2048*4;
  if ((size_t)(wp - (char*)d_ws) > ws_size) return;  // fail loudly

  setup_all<<<4096, 256, 0, stream>>>(
      bH, Wi2h, Wh2h, Whh, Wih, Wgen, bh2h, bih, bhh,
      bHh, Wi2h_h, Bh2_hi, Bh2_lo, Bih_hi, Bih_lo, Wg_hi, Wg_lo,
      WmT, WbT, bcombF, hA_hi, hA_lo, c);

  // proj = fp16( bHh @ Wi2h^T ), BK=64 ping-pong, XCD-aware 1D grid
  gemm_proj16<<<2048, 256, 36864, stream>>>(bHh, Wi2h_h, projh);

  for (int s=0; s<S_; ++s){
    // combo = h @ [W_h2h | W_hh]^T + [b_h2h | b_ih+b_hh]  (fused bf16x2)
    gemm_bf64<0><<<dim3(40,8), 256, 0, stream>>>(
        hA_hi, hA_lo, 512, Bh2_hi, Bh2_lo, 512,
        combo, 2560, bcombF);
    attn_kernel<<<B_, 1024, 0, stream>>>(
        projh, combo, Wsc, bHh, ctx_hi, ctx_lo);
    gates_lstm<<<dim3(32,8), 256, 0, stream>>>(
        ctx_hi, ctx_lo, Bih_hi, Bih_lo, combo, WmT, WbT,
        midt, bott, c, hA_hi, hA_lo,
        hid_hi, hid_lo, s);
  }

  // out = hid @ W_gen^T + b_gen  (fused bf16x2), M = S*B = 13312
  gemm_bf64<2><<<dim3(1,208), 256, 0, stream>>>(
      hid_hi, hid_lo, 512, Wg_hi, Wg_lo, 512,
      out, 0, bgen);
}